// Round 14
// baseline (4454.031 us; speedup 1.0000x reference)
//
#include <hip/hip_runtime.h>
#include <hip/hip_fp16.h>
#include <hip/hip_cooperative_groups.h>

namespace cg = cooperative_groups;

#define N_NODES 25000   // = 3125 * 8 exactly
#define E_EDGES 400000
#define KM 200      // message channels
#define RS 224      // A-row stride (floats): 200 fp32 A | 20 fp32 x | pad (896 B)
#define RSBH 224    // B-row stride (halfs): 200 fp16 B | 20 fp16 x | fp32 inv_p | fp32 inv_x (448 B)
#define EDGE_VB 1563  // ceil(E/256)
#define NODE_VB 3125  // N/8

__device__ __forceinline__ float2 h2f(unsigned u) {
  return __half22float2(*(const __half2*)&u);
}

struct Params {
  const float* features;
  const int* edges;
  const float *dW1, *db1, *dWm1, *dbm1, *dWm2, *dbm2, *dW2, *db2;
  const float *hW1, *hb1, *hWm1, *hbm1, *hWm2, *hbm2, *hW2, *hb2;
  const float *oW1, *ob1, *oWm1, *obm1, *oWm2, *obm2, *oW2, *ob2;
  float* A2;
  __half* Bh;
  float* gd;
  float* xrA;
  float* xrB;
  int* hist;
  int* off;
  int* cursor;
  int2* se;
  float* out;
};

// ---------------- phase device functions ----------------

// CSR scan: single block (others idle). 256 threads, ~98 nodes each.
__device__ void scan_block(const int* __restrict__ hist, int* __restrict__ off,
                           int* __restrict__ cursor) {
  __shared__ int sums[256];
  int tid = threadIdx.x;
  const int CH = (N_NODES + 255) / 256;  // 98
  int base = tid * CH;
  int s = 0;
  for (int i = 0; i < CH; i++) {
    int idx = base + i;
    if (idx < N_NODES) s += hist[idx];
  }
  sums[tid] = s;
  __syncthreads();
  for (int d = 1; d < 256; d <<= 1) {
    int v = (tid >= d) ? sums[tid - d] : 0;
    __syncthreads();
    sums[tid] += v;
    __syncthreads();
  }
  int run = (tid == 0) ? 0 : sums[tid - 1];
  for (int i = 0; i < CH; i++) {
    int idx = base + i;
    if (idx < N_NODES) {
      off[idx] = run;
      cursor[idx] = run;
      run += hist[idx];
    }
  }
  if (tid == 255) off[N_NODES] = run;  // == E
}

// prep (layer d): A fp32; B fp16 (bound-based scales). Weight maxes hoisted.
__device__ void prep_d_phase(const float* __restrict__ xin,
                             const float* __restrict__ Wm1, const float* __restrict__ bm1,
                             float* __restrict__ A2, __half* __restrict__ Bh,
                             float* __restrict__ xr, int bid, int gsz) {
  __shared__ unsigned wbmaxu;
  int k = threadIdx.x;
  if (k == 0) wbmaxu = 0;
  __syncthreads();
  float wa = 0.f, wb = 0.f, bm = 0.f;
  if (k < KM) {
    bm = bm1[k];
    wa = Wm1[k];
    wb = Wm1[KM + k];
  }
  float mb = (k < KM) ? fabsf(wb) : 0.f;
#pragma unroll
  for (int s = 1; s < 64; s <<= 1) mb = fmaxf(mb, __shfl_xor(mb, s));
  if ((k & 63) == 0) atomicMax(&wbmaxu, __float_as_uint(mb));
  __syncthreads();
  float wbmax = fmaxf(__uint_as_float(wbmaxu), 1e-30f);
  for (int vb = bid; vb < NODE_VB; vb += gsz) {
    int n0 = vb * 8;
    for (int i = 0; i < 8; i++) {
      int n = n0 + i;
      float xv = xin[n];
      float bBound = fmaxf(fabsf(xv) * wbmax, 1e-30f);
      float xBound = fmaxf(fabsf(xv), 1e-30f);
      size_t rowA = (size_t)n * RS;
      __half* rb = Bh + (size_t)n * RSBH;
      if (k == 0) {
        xr[n] = xv;
        A2[rowA + KM] = xv;
        rb[200] = __float2half(xv * (32768.f / xBound));
        *(float*)(rb + 220) = bBound / 32768.f;
        *(float*)(rb + 222) = xBound / 32768.f;
      }
      if (k < KM) {
        A2[rowA + k] = bm + xv * wa;
        rb[k] = __float2half(xv * wb * (32768.f / bBound));
      }
    }
  }
}

// Edge phase: one thread per (dst-sorted) edge; A fp32 streamed, B fp16 gathered.
template <int CIN>
__device__ void edge_phase(const int2* __restrict__ se,
                           const float* __restrict__ A2, const __half* __restrict__ Bh,
                           const float* __restrict__ Wm2, const float* __restrict__ bm2,
                           float* __restrict__ gd, int bid, int gsz) {
  for (int vb = bid; vb < EDGE_VB; vb += gsz) {
    int e = vb * 256 + (int)threadIdx.x;
    if (e >= E_EDGES) continue;
    int2 sd = se[e];
    int src = sd.x;
    int dst = sd.y;
    const float* Ar = A2 + (size_t)dst * RS;
    const __half* Br = Bh + (size_t)src * RSBH;
    float invB = *(const float*)(Br + 220);
    float gate[CIN];
#pragma unroll
    for (int c = 0; c < CIN; c++) gate[c] = bm2[c];
#pragma unroll 2
    for (int k = 0; k < KM; k += 8) {
      float4 a0 = *(const float4*)(Ar + k);
      float4 a1 = *(const float4*)(Ar + k + 4);
      uint4 braw = *(const uint4*)(Br + k);  // 8 fp16
      float2 f0 = h2f(braw.x), f1 = h2f(braw.y), f2 = h2f(braw.z), f3 = h2f(braw.w);
      float h[8];
      h[0] = fmaxf(a0.x + f0.x * invB, 0.f);
      h[1] = fmaxf(a0.y + f0.y * invB, 0.f);
      h[2] = fmaxf(a0.z + f1.x * invB, 0.f);
      h[3] = fmaxf(a0.w + f1.y * invB, 0.f);
      h[4] = fmaxf(a1.x + f2.x * invB, 0.f);
      h[5] = fmaxf(a1.y + f2.y * invB, 0.f);
      h[6] = fmaxf(a1.z + f3.x * invB, 0.f);
      h[7] = fmaxf(a1.w + f3.y * invB, 0.f);
#pragma unroll
      for (int c = 0; c < CIN; c++) {
        float g = gate[c];
#pragma unroll
        for (int j = 0; j < 8; j++) g += h[j] * Wm2[(k + j) * CIN + c];
        gate[c] = g;
      }
    }
    float invXb = *(const float*)(Br + 222);
    if constexpr (CIN == 20) {
      unsigned wxb[10];
      {
        uint4 s0 = *(const uint4*)(Br + 200);
        uint4 s1 = *(const uint4*)(Br + 208);
        uint2 s2 = *(const uint2*)(Br + 216);
        wxb[0] = s0.x; wxb[1] = s0.y; wxb[2] = s0.z; wxb[3] = s0.w;
        wxb[4] = s1.x; wxb[5] = s1.y; wxb[6] = s1.z; wxb[7] = s1.w;
        wxb[8] = s2.x; wxb[9] = s2.y;
      }
#pragma unroll
      for (int i = 0; i < 10; i++) {
        float2 xa = *(const float2*)(Ar + KM + 2 * i);
        float2 fb = h2f(wxb[i]);
        int c0 = 2 * i, c1 = 2 * i + 1;
        __builtin_nontemporal_store(gate[c0] * (xa.x - fb.x * invXb),
                                    gd + (size_t)c0 * E_EDGES + e);
        __builtin_nontemporal_store(gate[c1] * (xa.y - fb.y * invXb),
                                    gd + (size_t)c1 * E_EDGES + e);
      }
    } else {
      float xa = Ar[KM];
      float xb = __half2float(Br[200]) * invXb;
      __builtin_nontemporal_store(gate[0] * (xa - xb), gd + e);
    }
  }
}

// afp1: agg(1ch, 64-thread) + fin(1->20)+relu + prep-next (B fp16 exact-scaled).
__device__ void afp1_phase(const float* __restrict__ gd, const int* __restrict__ off,
                           const float* __restrict__ xrp,
                           const float* __restrict__ W1, const float* __restrict__ b1,
                           const float* __restrict__ W2, const float* __restrict__ b2,
                           const float* __restrict__ Wm1n, const float* __restrict__ bm1n,
                           float* __restrict__ A2, __half* __restrict__ Bh,
                           float* __restrict__ xrn, int bid, int gsz) {
  __shared__ float ag1[8], xp1[8], degs1[8];
  __shared__ float xv1[8][21];
  __shared__ unsigned bmaxu1[8];
  __shared__ float xmaxs1[8];
  int tid = threadIdx.x;
  int k = tid;
  float wa[20], wb[20], bm = 0.f;
  if (k < KM) {
    bm = bm1n[k];
#pragma unroll
    for (int c = 0; c < 20; c++) {
      wa[c] = Wm1n[c * KM + k];
      wb[c] = Wm1n[(20 + c) * KM + k];
    }
  }
  for (int vb = bid; vb < NODE_VB; vb += gsz) {
    int n0 = vb * 8;
    if (tid < 8) bmaxu1[tid] = 0;
    if (tid < 64) {
      int nl = tid >> 3, j = tid & 7;
      int n = n0 + nl;
      int s = off[n], t = off[n + 1];
      float v = 0.f;
      for (int e = s + j; e < t; e += 8) v += gd[e];
      v += __shfl_xor(v, 1);
      v += __shfl_xor(v, 2);
      v += __shfl_xor(v, 4);
      if (j == 0) {
        ag1[nl] = v;
        xp1[nl] = xrp[n];
        degs1[nl] = (float)(t - s);
      }
    }
    __syncthreads();
    if (tid < 160) {
      int o = tid >> 3, nl = tid & 7;
      float v = b1[o] + degs1[nl] * b2[o] + ag1[nl] * W2[o] + xp1[nl] * W1[o];
      float r = fmaxf(v, 0.f);
      xv1[nl][o] = r;
      xrn[(n0 + nl) * 20 + o] = r;
    }
    __syncthreads();
    if (tid < 8) {
      float m = 0.f;
#pragma unroll
      for (int c = 0; c < 20; c++) m = fmaxf(m, xv1[tid][c]);
      xmaxs1[tid] = fmaxf(m, 1e-30f);
    }
    float aa[8], bb[8];
    if (k < KM) {
#pragma unroll
      for (int nl = 0; nl < 8; nl++) {
        float a = bm, b = 0.f;
#pragma unroll
        for (int c = 0; c < 20; c++) {
          a += xv1[nl][c] * wa[c];
          b += xv1[nl][c] * wb[c];
        }
        aa[nl] = a;
        bb[nl] = b;
      }
    }
    float mxb[8];
#pragma unroll
    for (int nl = 0; nl < 8; nl++) mxb[nl] = (k < KM) ? fabsf(bb[nl]) : 0.f;
#pragma unroll
    for (int s = 1; s < 64; s <<= 1) {
#pragma unroll
      for (int nl = 0; nl < 8; nl++) mxb[nl] = fmaxf(mxb[nl], __shfl_xor(mxb[nl], s));
    }
    if ((tid & 63) == 0) {
#pragma unroll
      for (int nl = 0; nl < 8; nl++) atomicMax(&bmaxu1[nl], __float_as_uint(mxb[nl]));
    }
    __syncthreads();
    if (k < KM) {
#pragma unroll
      for (int nl = 0; nl < 8; nl++) {
        float bmax = fmaxf(__uint_as_float(bmaxu1[nl]), 1e-30f);
        float xmax = xmaxs1[nl];
        size_t rowA = (size_t)(n0 + nl) * RS;
        __half* rb = Bh + (size_t)(n0 + nl) * RSBH;
        A2[rowA + k] = aa[nl];
        rb[k] = __float2half(bb[nl] * (32768.f / bmax));
        if (k < 20) {
          A2[rowA + KM + k] = xv1[nl][k];
          rb[200 + k] = __float2half(xv1[nl][k] * (32768.f / xmax));
        }
        if (k == 0) {
          *(float*)(rb + 220) = bmax / 32768.f;
          *(float*)(rb + 222) = xmax / 32768.f;
        }
      }
    }
    __syncthreads();  // LDS reuse guard
  }
}

// afp20: agg(20ch) + fin(20->20)+relu + prep-next.
__device__ void afp20_phase(const float* __restrict__ gd, const int* __restrict__ off,
                            const float* __restrict__ xrp,
                            const float* __restrict__ W1, const float* __restrict__ b1,
                            const float* __restrict__ W2, const float* __restrict__ b2,
                            const float* __restrict__ Wm1n, const float* __restrict__ bm1n,
                            float* __restrict__ A2, __half* __restrict__ Bh,
                            float* __restrict__ xrn, int bid, int gsz) {
  __shared__ float ag[8][21], xp[8][21], xv[8][21], degs[8];
  __shared__ unsigned bmaxu[8];
  __shared__ float xmaxs[8];
  int tid = threadIdx.x;
  int k = tid;
  float wa[20], wb[20], bm = 0.f;
  if (k < KM) {
    bm = bm1n[k];
#pragma unroll
    for (int c = 0; c < 20; c++) {
      wa[c] = Wm1n[c * KM + k];
      wb[c] = Wm1n[(20 + c) * KM + k];
    }
  }
  for (int vb = bid; vb < NODE_VB; vb += gsz) {
    int n0 = vb * 8;
    if (tid < 8) bmaxu[tid] = 0;
    if (tid < 160) {
      int c = tid >> 3, nl = tid & 7;  // adjacent lanes: same c, adjacent n
      int n = n0 + nl;
      int s = off[n], t = off[n + 1];
      const float* g = gd + (size_t)c * E_EDGES;
      float v = 0.f;
      for (int e = s; e < t; e++) v += g[e];
      ag[nl][c] = v;
      xp[nl][c] = xrp[n * 20 + c];
      if (c == 0) degs[nl] = (float)(t - s);
    }
    __syncthreads();
    if (tid < 160) {
      int o = tid >> 3, nl = tid & 7;
      float v = b1[o] + degs[nl] * b2[o];
#pragma unroll
      for (int c = 0; c < 20; c++) {
        v += ag[nl][c] * W2[c * 20 + o] + xp[nl][c] * W1[c * 20 + o];
      }
      float r = fmaxf(v, 0.f);
      xv[nl][o] = r;
      xrn[(n0 + nl) * 20 + o] = r;
    }
    __syncthreads();
    if (tid < 8) {
      float m = 0.f;
#pragma unroll
      for (int c = 0; c < 20; c++) m = fmaxf(m, xv[tid][c]);
      xmaxs[tid] = fmaxf(m, 1e-30f);
    }
    float aa[8], bb[8];
    if (k < KM) {
#pragma unroll
      for (int nl = 0; nl < 8; nl++) {
        float a = bm, b = 0.f;
#pragma unroll
        for (int c = 0; c < 20; c++) {
          a += xv[nl][c] * wa[c];
          b += xv[nl][c] * wb[c];
        }
        aa[nl] = a;
        bb[nl] = b;
      }
    }
    float mxb[8];
#pragma unroll
    for (int nl = 0; nl < 8; nl++) mxb[nl] = (k < KM) ? fabsf(bb[nl]) : 0.f;
#pragma unroll
    for (int s = 1; s < 64; s <<= 1) {
#pragma unroll
      for (int nl = 0; nl < 8; nl++) mxb[nl] = fmaxf(mxb[nl], __shfl_xor(mxb[nl], s));
    }
    if ((tid & 63) == 0) {
#pragma unroll
      for (int nl = 0; nl < 8; nl++) atomicMax(&bmaxu[nl], __float_as_uint(mxb[nl]));
    }
    __syncthreads();
    if (k < KM) {
#pragma unroll
      for (int nl = 0; nl < 8; nl++) {
        float bmax = fmaxf(__uint_as_float(bmaxu[nl]), 1e-30f);
        float xmax = xmaxs[nl];
        size_t rowA = (size_t)(n0 + nl) * RS;
        __half* rb = Bh + (size_t)(n0 + nl) * RSBH;
        A2[rowA + k] = aa[nl];
        rb[k] = __float2half(bb[nl] * (32768.f / bmax));
        if (k < 20) {
          A2[rowA + KM + k] = xv[nl][k];
          rb[200 + k] = __float2half(xv[nl][k] * (32768.f / xmax));
        }
        if (k == 0) {
          *(float*)(rb + 220) = bmax / 32768.f;
          *(float*)(rb + 222) = xmax / 32768.f;
        }
      }
    }
    __syncthreads();  // LDS reuse guard
  }
}

// final: agg(20ch) + fin(20->1), no relu, writes out.
__device__ void aggfin_out_phase(const float* __restrict__ gd, const int* __restrict__ off,
                                 const float* __restrict__ xrp,
                                 const float* __restrict__ W1, const float* __restrict__ b1,
                                 const float* __restrict__ W2, const float* __restrict__ b2,
                                 float* __restrict__ out, int bid, int gsz) {
  __shared__ float ago[8][21], xpo[8][21], dego[8];
  int tid = threadIdx.x;
  for (int vb = bid; vb < NODE_VB; vb += gsz) {
    int n0 = vb * 8;
    if (tid < 160) {
      int c = tid >> 3, nl = tid & 7;
      int n = n0 + nl;
      int s = off[n], t = off[n + 1];
      const float* g = gd + (size_t)c * E_EDGES;
      float v = 0.f;
      for (int e = s; e < t; e++) v += g[e];
      ago[nl][c] = v;
      xpo[nl][c] = xrp[n * 20 + c];
      if (c == 0) dego[nl] = (float)(t - s);
    }
    __syncthreads();
    if (tid < 8) {
      float v = b1[0] + dego[tid] * b2[0];
#pragma unroll
      for (int c = 0; c < 20; c++) {
        v += ago[tid][c] * W2[c] + xpo[tid][c] * W1[c];
      }
      out[n0 + tid] = v;
    }
    __syncthreads();
  }
}

// ---------------- the mega-kernel ----------------

__global__ void __launch_bounds__(256, 6) mega_kernel(Params p) {
  cg::grid_group grid = cg::this_grid();
  const int tid = threadIdx.x;
  const int bid = blockIdx.x;
  const int gsz = gridDim.x;
  const int gtid = bid * 256 + tid;
  const int gth = gsz * 256;

  // S0: zero hist
  for (int i = gtid; i < N_NODES; i += gth) p.hist[i] = 0;
  __threadfence();
  grid.sync();
  // S1: histogram of dst
  for (int e = gtid; e < E_EDGES; e += gth) atomicAdd(&p.hist[p.edges[E_EDGES + e]], 1);
  __threadfence();
  grid.sync();
  // S2: scan (block 0) || prep_d (all blocks)
  if (bid == 0) scan_block(p.hist, p.off, p.cursor);
  prep_d_phase(p.features, p.dWm1, p.dbm1, p.A2, p.Bh, p.xrA, bid, gsz);
  __threadfence();
  grid.sync();
  // S3: scatter into dst-sorted (src,dst) pairs
  for (int e = gtid; e < E_EDGES; e += gth) {
    int s = p.edges[e];
    int d = p.edges[E_EDGES + e];
    int pos = atomicAdd(&p.cursor[d], 1);
    p.se[pos] = make_int2(s, d);
  }
  __threadfence();
  grid.sync();
  // layer d: 1 -> 20
  edge_phase<1>(p.se, p.A2, p.Bh, p.dWm2, p.dbm2, p.gd, bid, gsz);
  __threadfence();
  grid.sync();
  afp1_phase(p.gd, p.off, p.xrA, p.dW1, p.db1, p.dW2, p.db2, p.hWm1, p.hbm1,
             p.A2, p.Bh, p.xrB, bid, gsz);
  __threadfence();
  grid.sync();
  // hidden1
  edge_phase<20>(p.se, p.A2, p.Bh, p.hWm2, p.hbm2, p.gd, bid, gsz);
  __threadfence();
  grid.sync();
  afp20_phase(p.gd, p.off, p.xrB, p.hW1, p.hb1, p.hW2, p.hb2, p.hWm1, p.hbm1,
              p.A2, p.Bh, p.xrA, bid, gsz);
  __threadfence();
  grid.sync();
  // hidden2
  edge_phase<20>(p.se, p.A2, p.Bh, p.hWm2, p.hbm2, p.gd, bid, gsz);
  __threadfence();
  grid.sync();
  afp20_phase(p.gd, p.off, p.xrA, p.hW1, p.hb1, p.hW2, p.hb2, p.hWm1, p.hbm1,
              p.A2, p.Bh, p.xrB, bid, gsz);
  __threadfence();
  grid.sync();
  // hidden3 -> preps output layer (oWm1)
  edge_phase<20>(p.se, p.A2, p.Bh, p.hWm2, p.hbm2, p.gd, bid, gsz);
  __threadfence();
  grid.sync();
  afp20_phase(p.gd, p.off, p.xrB, p.hW1, p.hb1, p.hW2, p.hb2, p.oWm1, p.obm1,
              p.A2, p.Bh, p.xrA, bid, gsz);
  __threadfence();
  grid.sync();
  // output layer: 20 -> 1 (no trailing relu)
  edge_phase<20>(p.se, p.A2, p.Bh, p.oWm2, p.obm2, p.gd, bid, gsz);
  __threadfence();
  grid.sync();
  aggfin_out_phase(p.gd, p.off, p.xrA, p.oW1, p.ob1, p.oW2, p.ob2, p.out, bid, gsz);
}

// ---------------- launch ----------------

extern "C" void kernel_launch(void* const* d_in, const int* in_sizes, int n_in,
                              void* d_out, int out_size, void* d_ws, size_t ws_size,
                              hipStream_t stream) {
  Params p;
  p.features = (const float*)d_in[0];
  p.edges = (const int*)d_in[1];
  // d_in[2] = weights (unused by reference)
  p.dW1 = (const float*)d_in[3];  p.db1 = (const float*)d_in[4];
  p.dWm1 = (const float*)d_in[5]; p.dbm1 = (const float*)d_in[6];
  p.dWm2 = (const float*)d_in[7]; p.dbm2 = (const float*)d_in[8];
  p.dW2 = (const float*)d_in[9];  p.db2 = (const float*)d_in[10];
  p.hW1 = (const float*)d_in[11]; p.hb1 = (const float*)d_in[12];
  p.hWm1 = (const float*)d_in[13]; p.hbm1 = (const float*)d_in[14];
  p.hWm2 = (const float*)d_in[15]; p.hbm2 = (const float*)d_in[16];
  p.hW2 = (const float*)d_in[17]; p.hb2 = (const float*)d_in[18];
  p.oW1 = (const float*)d_in[19]; p.ob1 = (const float*)d_in[20];
  p.oWm1 = (const float*)d_in[21]; p.obm1 = (const float*)d_in[22];
  p.oWm2 = (const float*)d_in[23]; p.obm2 = (const float*)d_in[24];
  p.oW2 = (const float*)d_in[25]; p.ob2 = (const float*)d_in[26];

  // workspace layout (float units)
  float* fws = (float*)d_ws;
  size_t o = 0;
  p.A2 = fws + o;             o += (size_t)N_NODES * RS;        // 5.6M
  p.Bh = (__half*)(fws + o);  o += (size_t)N_NODES * RSBH / 2;  // 2.8M floats
  p.gd = fws + o;             o += (size_t)20 * E_EDGES;        // 8.0M ([c][e])
  p.xrA = fws + o;            o += (size_t)N_NODES * 20;
  p.xrB = fws + o;            o += (size_t)N_NODES * 20;
  int* ip = (int*)(fws + o);
  p.hist = ip;   ip += N_NODES;
  p.off = ip;    ip += N_NODES + 4;
  p.cursor = ip; ip += N_NODES;
  p.se = (int2*)ip;
  p.out = (float*)d_out;

  int nb = 0;
  (void)hipOccupancyMaxActiveBlocksPerMultiprocessor(&nb, mega_kernel, 256, 0);
  if (nb < 1) nb = 1;
  long grid = (long)nb * 256;  // MI355X: 256 CUs
  if (grid > EDGE_VB) grid = EDGE_VB;

  void* kargs[] = {(void*)&p};
  (void)hipLaunchCooperativeKernel(mega_kernel, dim3((unsigned)grid), dim3(256),
                                   kargs, 0, stream);
}

// Round 15
// 785.062 us; speedup vs baseline: 5.6735x; 5.6735x over previous
//
#include <hip/hip_runtime.h>
#include <hip/hip_fp16.h>

#define N_NODES 25000   // = 3125 * 8 exactly
#define E_EDGES 400000
#define KM 200      // message channels
#define RS 224      // A-row stride (floats): 200 fp32 A | 20 fp32 x | pad (896 B)
#define RSB 256     // B-row stride BYTES: 200 int8 | pad | 20 fp16 x @208 | inv_p,inv_x @248

__device__ __forceinline__ float2 h2f(unsigned u) {
  return __half22float2(*(const __half2*)&u);
}
__device__ __forceinline__ float4 i8x4f(unsigned u) {
  float4 f;
  f.x = (float)((int)(u << 24) >> 24);
  f.y = (float)((int)(u << 16) >> 24);
  f.z = (float)((int)(u << 8) >> 24);
  f.w = (float)((int)u >> 24);
  return f;
}

// ---------------- sort-by-dst (CSR build) ----------------

__global__ void hist_kernel(const int* __restrict__ edges, int* __restrict__ hist) {
  int e = blockIdx.x * blockDim.x + threadIdx.x;
  if (e < E_EDGES) atomicAdd(&hist[edges[E_EDGES + e]], 1);
}

__global__ void scan_kernel(const int* __restrict__ hist, int* __restrict__ off,
                            int* __restrict__ cursor) {
  __shared__ int sums[1024];
  const int CH = (N_NODES + 1023) / 1024;  // 25
  int tid = threadIdx.x;
  int base = tid * CH;
  int s = 0;
  for (int i = 0; i < CH; i++) {
    int idx = base + i;
    if (idx < N_NODES) s += hist[idx];
  }
  sums[tid] = s;
  __syncthreads();
  for (int d = 1; d < 1024; d <<= 1) {
    int v = (tid >= d) ? sums[tid - d] : 0;
    __syncthreads();
    sums[tid] += v;
    __syncthreads();
  }
  int run = (tid == 0) ? 0 : sums[tid - 1];
  for (int i = 0; i < CH; i++) {
    int idx = base + i;
    if (idx < N_NODES) {
      off[idx] = run;
      cursor[idx] = run;
      run += hist[idx];
    }
  }
  if (tid == 1023) off[N_NODES] = run;  // == E
}

// ---------------- per-layer kernels ----------------

// Fused: scatter (128 edges/block) + prep layer-d (8 nodes/block).
// prep: A fp32; B int8 (exact bound: max_k |x*wb_k| = |x|*wbmax); x-tail fp16.
__global__ void __launch_bounds__(256) scatter_prep_d_kernel(
    const int* __restrict__ edges, int* __restrict__ cursor, int2* __restrict__ se,
    const float* __restrict__ xin,
    const float* __restrict__ Wm1, const float* __restrict__ bm1,
    float* __restrict__ A2, unsigned char* __restrict__ Bq, float* __restrict__ xr) {
  int tid = threadIdx.x;
  // scatter part: 3125 * 128 = 400000 exactly
  if (tid < 128) {
    int e = blockIdx.x * 128 + tid;
    int s = edges[e];
    int d = edges[E_EDGES + e];
    int pos = atomicAdd(&cursor[d], 1);
    se[pos] = make_int2(s, d);
  }
  // prep part
  __shared__ unsigned wbmaxu;
  if (tid == 0) wbmaxu = 0;
  __syncthreads();
  int k = tid;
  float wa = 0.f, wb = 0.f, bm = 0.f;
  if (k < KM) {
    bm = bm1[k];
    wa = Wm1[k];
    wb = Wm1[KM + k];
  }
  float mb = (k < KM) ? fabsf(wb) : 0.f;
#pragma unroll
  for (int s = 1; s < 64; s <<= 1) mb = fmaxf(mb, __shfl_xor(mb, s));
  if ((k & 63) == 0) atomicMax(&wbmaxu, __float_as_uint(mb));
  __syncthreads();
  float wbmax = fmaxf(__uint_as_float(wbmaxu), 1e-30f);
  int n0 = blockIdx.x * 8;
  for (int i = 0; i < 8; i++) {
    int n = n0 + i;
    float xv = xin[n];
    float bBound = fmaxf(fabsf(xv) * wbmax, 1e-30f);
    float xBound = fmaxf(fabsf(xv), 1e-30f);
    size_t rowA = (size_t)n * RS;
    unsigned char* rb = Bq + (size_t)n * RSB;
    if (k == 0) {
      xr[n] = xv;
      A2[rowA + KM] = xv;
      ((__half*)(rb + 208))[0] = __float2half(xv * (32768.f / xBound));
      ((float*)(rb + 248))[0] = bBound / 127.f;
      ((float*)(rb + 248))[1] = xBound / 32768.f;
    }
    if (k < KM) {
      A2[rowA + k] = bm + xv * wa;
      rb[k] = (unsigned char)(signed char)lrintf(xv * wb * (127.f / bBound));
    }
  }
}

// Edge kernel: one thread per (dst-sorted) edge. A fp32 (dst-shared, streamed),
// B int8 256 B (randomly gathered — the HBM-duplication term, 4 lines/row).
// h_k = relu(A[dst][k] + B8[src][k]*invB); gate = h@Wm2 + bm2;
// gd layout [c][e]: coalesced nontemporal dword stores.
template <int CIN>
__global__ void __launch_bounds__(256) edge_kernel(
    const int2* __restrict__ se,
    const float* __restrict__ A2, const unsigned char* __restrict__ Bq,
    const float* __restrict__ Wm2, const float* __restrict__ bm2,
    float* __restrict__ gd) {
  int e = blockIdx.x * 256 + threadIdx.x;
  if (e >= E_EDGES) return;
  int2 sd = se[e];
  int src = sd.x;
  int dst = sd.y;
  const float* Ar = A2 + (size_t)dst * RS;
  const unsigned char* Br = Bq + (size_t)src * RSB;
  float invB = ((const float*)(Br + 248))[0];
  float gate[CIN];
#pragma unroll
  for (int c = 0; c < CIN; c++) gate[c] = bm2[c];
#pragma unroll 2
  for (int k = 0; k < KM; k += 8) {
    float4 a0 = *(const float4*)(Ar + k);
    float4 a1 = *(const float4*)(Ar + k + 4);
    uint2 braw = *(const uint2*)(Br + k);  // 8 int8
    float4 f01 = i8x4f(braw.x);
    float4 f23 = i8x4f(braw.y);
    float h[8];
    h[0] = fmaxf(a0.x + f01.x * invB, 0.f);
    h[1] = fmaxf(a0.y + f01.y * invB, 0.f);
    h[2] = fmaxf(a0.z + f01.z * invB, 0.f);
    h[3] = fmaxf(a0.w + f01.w * invB, 0.f);
    h[4] = fmaxf(a1.x + f23.x * invB, 0.f);
    h[5] = fmaxf(a1.y + f23.y * invB, 0.f);
    h[6] = fmaxf(a1.z + f23.z * invB, 0.f);
    h[7] = fmaxf(a1.w + f23.w * invB, 0.f);
#pragma unroll
    for (int c = 0; c < CIN; c++) {
      float g = gate[c];
#pragma unroll
      for (int j = 0; j < 8; j++) g += h[j] * Wm2[(k + j) * CIN + c];
      gate[c] = g;
    }
  }
  // x-diff tails: A fp32, B fp16-scaled; coalesced nontemporal stores
  float invXb = ((const float*)(Br + 248))[1];
  const __half* xtb = (const __half*)(Br + 208);
  if constexpr (CIN == 20) {
    unsigned wxb[10];
    {
      uint4 s0 = *(const uint4*)(xtb);
      uint4 s1 = *(const uint4*)(xtb + 8);
      uint2 s2 = *(const uint2*)(xtb + 16);
      wxb[0] = s0.x; wxb[1] = s0.y; wxb[2] = s0.z; wxb[3] = s0.w;
      wxb[4] = s1.x; wxb[5] = s1.y; wxb[6] = s1.z; wxb[7] = s1.w;
      wxb[8] = s2.x; wxb[9] = s2.y;
    }
#pragma unroll
    for (int i = 0; i < 10; i++) {
      float2 xa = *(const float2*)(Ar + KM + 2 * i);
      float2 fb = h2f(wxb[i]);
      int c0 = 2 * i, c1 = 2 * i + 1;
      __builtin_nontemporal_store(gate[c0] * (xa.x - fb.x * invXb),
                                  gd + (size_t)c0 * E_EDGES + e);
      __builtin_nontemporal_store(gate[c1] * (xa.y - fb.y * invXb),
                                  gd + (size_t)c1 * E_EDGES + e);
    }
  } else {
    float xa = Ar[KM];
    float xb = __half2float(xtb[0]) * invXb;
    __builtin_nontemporal_store(gate[0] * (xa - xb), gd + e);
  }
}

// afp1: after layer-d edge (gd 1-channel). Per block: 8 nodes.
//  phase1 agg; phase2 fin(1->20)+relu -> xv,xrn; phase3 prep (A fp32, B int8 exact-scaled).
__global__ void __launch_bounds__(256) afp1_kernel(
    const float* __restrict__ gd, const int* __restrict__ off,
    const float* __restrict__ xrp,
    const float* __restrict__ W1, const float* __restrict__ b1,
    const float* __restrict__ W2, const float* __restrict__ b2,
    const float* __restrict__ Wm1n, const float* __restrict__ bm1n,
    float* __restrict__ A2, unsigned char* __restrict__ Bq, float* __restrict__ xrn) {
  __shared__ float ag[8], xp[8], degs[8];
  __shared__ float xv[8][21];
  __shared__ unsigned bmaxu[8];
  __shared__ float xmaxs[8];
  int tid = threadIdx.x;
  int n0 = blockIdx.x * 8;
  if (tid < 8) {
    bmaxu[tid] = 0;
    int n = n0 + tid;
    int s = off[n], t = off[n + 1];
    float v = 0.f;
    for (int e = s; e < t; e++) v += gd[e];
    ag[tid] = v;
    xp[tid] = xrp[n];
    degs[tid] = (float)(t - s);
  }
  __syncthreads();
  if (tid < 160) {
    int o = tid >> 3, nl = tid & 7;
    float v = b1[o] + degs[nl] * b2[o] + ag[nl] * W2[o] + xp[nl] * W1[o];
    float r = fmaxf(v, 0.f);
    xv[nl][o] = r;
    xrn[(n0 + nl) * 20 + o] = r;
  }
  __syncthreads();
  if (tid < 8) {
    float m = 0.f;
#pragma unroll
    for (int c = 0; c < 20; c++) m = fmaxf(m, xv[tid][c]);
    xmaxs[tid] = fmaxf(m, 1e-30f);
  }
  int k = tid;
  float aa[8], bb[8];
  if (k < KM) {
    float wa[20], wb[20];
    float bm = bm1n[k];
#pragma unroll
    for (int c = 0; c < 20; c++) {
      wa[c] = Wm1n[c * KM + k];
      wb[c] = Wm1n[(20 + c) * KM + k];
    }
#pragma unroll
    for (int nl = 0; nl < 8; nl++) {
      float a = bm, b = 0.f;
#pragma unroll
      for (int c = 0; c < 20; c++) {
        a += xv[nl][c] * wa[c];
        b += xv[nl][c] * wb[c];
      }
      aa[nl] = a;
      bb[nl] = b;
    }
  }
  float mxb[8];
#pragma unroll
  for (int nl = 0; nl < 8; nl++) mxb[nl] = (k < KM) ? fabsf(bb[nl]) : 0.f;
#pragma unroll
  for (int s = 1; s < 64; s <<= 1) {
#pragma unroll
    for (int nl = 0; nl < 8; nl++) mxb[nl] = fmaxf(mxb[nl], __shfl_xor(mxb[nl], s));
  }
  if ((tid & 63) == 0) {
#pragma unroll
    for (int nl = 0; nl < 8; nl++) atomicMax(&bmaxu[nl], __float_as_uint(mxb[nl]));
  }
  __syncthreads();
  if (k < KM) {
#pragma unroll
    for (int nl = 0; nl < 8; nl++) {
      float bmax = fmaxf(__uint_as_float(bmaxu[nl]), 1e-30f);
      float xmax = xmaxs[nl];
      size_t rowA = (size_t)(n0 + nl) * RS;
      unsigned char* rb = Bq + (size_t)(n0 + nl) * RSB;
      A2[rowA + k] = aa[nl];
      rb[k] = (unsigned char)(signed char)lrintf(bb[nl] * (127.f / bmax));
      if (k < 20) {
        A2[rowA + KM + k] = xv[nl][k];
        ((__half*)(rb + 208))[k] = __float2half(xv[nl][k] * (32768.f / xmax));
      }
      if (k == 0) {
        ((float*)(rb + 248))[0] = bmax / 127.f;
        ((float*)(rb + 248))[1] = xmax / 32768.f;
      }
    }
  }
}

// afp20: after a hidden edge (gd 20-channel). Same 3 phases, CIN=20.
__global__ void __launch_bounds__(256) afp20_kernel(
    const float* __restrict__ gd, const int* __restrict__ off,
    const float* __restrict__ xrp,
    const float* __restrict__ W1, const float* __restrict__ b1,
    const float* __restrict__ W2, const float* __restrict__ b2,
    const float* __restrict__ Wm1n, const float* __restrict__ bm1n,
    float* __restrict__ A2, unsigned char* __restrict__ Bq, float* __restrict__ xrn) {
  __shared__ float ag[8][21], xp[8][21], xv[8][21], degs[8];
  __shared__ unsigned bmaxu[8];
  __shared__ float xmaxs[8];
  int tid = threadIdx.x;
  int n0 = blockIdx.x * 8;
  if (tid < 8) bmaxu[tid] = 0;
  if (tid < 160) {
    int c = tid >> 3, nl = tid & 7;  // adjacent lanes: same c, adjacent n
    int n = n0 + nl;
    int s = off[n], t = off[n + 1];
    const float* g = gd + (size_t)c * E_EDGES;
    float v = 0.f;
    for (int e = s; e < t; e++) v += g[e];
    ag[nl][c] = v;
    xp[nl][c] = xrp[n * 20 + c];
    if (c == 0) degs[nl] = (float)(t - s);
  }
  __syncthreads();
  if (tid < 160) {
    int o = tid >> 3, nl = tid & 7;
    float v = b1[o] + degs[nl] * b2[o];
#pragma unroll
    for (int c = 0; c < 20; c++) {
      v += ag[nl][c] * W2[c * 20 + o] + xp[nl][c] * W1[c * 20 + o];
    }
    float r = fmaxf(v, 0.f);
    xv[nl][o] = r;
    xrn[(n0 + nl) * 20 + o] = r;
  }
  __syncthreads();
  if (tid < 8) {
    float m = 0.f;
#pragma unroll
    for (int c = 0; c < 20; c++) m = fmaxf(m, xv[tid][c]);
    xmaxs[tid] = fmaxf(m, 1e-30f);
  }
  int k = tid;
  float aa[8], bb[8];
  if (k < KM) {
    float wa[20], wb[20];
    float bm = bm1n[k];
#pragma unroll
    for (int c = 0; c < 20; c++) {
      wa[c] = Wm1n[c * KM + k];
      wb[c] = Wm1n[(20 + c) * KM + k];
    }
#pragma unroll
    for (int nl = 0; nl < 8; nl++) {
      float a = bm, b = 0.f;
#pragma unroll
      for (int c = 0; c < 20; c++) {
        a += xv[nl][c] * wa[c];
        b += xv[nl][c] * wb[c];
      }
      aa[nl] = a;
      bb[nl] = b;
    }
  }
  float mxb[8];
#pragma unroll
  for (int nl = 0; nl < 8; nl++) mxb[nl] = (k < KM) ? fabsf(bb[nl]) : 0.f;
#pragma unroll
  for (int s = 1; s < 64; s <<= 1) {
#pragma unroll
    for (int nl = 0; nl < 8; nl++) mxb[nl] = fmaxf(mxb[nl], __shfl_xor(mxb[nl], s));
  }
  if ((tid & 63) == 0) {
#pragma unroll
    for (int nl = 0; nl < 8; nl++) atomicMax(&bmaxu[nl], __float_as_uint(mxb[nl]));
  }
  __syncthreads();
  if (k < KM) {
#pragma unroll
    for (int nl = 0; nl < 8; nl++) {
      float bmax = fmaxf(__uint_as_float(bmaxu[nl]), 1e-30f);
      float xmax = xmaxs[nl];
      size_t rowA = (size_t)(n0 + nl) * RS;
      unsigned char* rb = Bq + (size_t)(n0 + nl) * RSB;
      A2[rowA + k] = aa[nl];
      rb[k] = (unsigned char)(signed char)lrintf(bb[nl] * (127.f / bmax));
      if (k < 20) {
        A2[rowA + KM + k] = xv[nl][k];
        ((__half*)(rb + 208))[k] = __float2half(xv[nl][k] * (32768.f / xmax));
      }
      if (k == 0) {
        ((float*)(rb + 248))[0] = bmax / 127.f;
        ((float*)(rb + 248))[1] = xmax / 32768.f;
      }
    }
  }
}

// final: agg(20ch) + fin(20->1), no relu, writes d_out.
__global__ void __launch_bounds__(256) aggfin_out_kernel(
    const float* __restrict__ gd, const int* __restrict__ off,
    const float* __restrict__ xrp,
    const float* __restrict__ W1, const float* __restrict__ b1,
    const float* __restrict__ W2, const float* __restrict__ b2,
    float* __restrict__ out) {
  __shared__ float ag[8][21], xp[8][21], degs[8];
  int tid = threadIdx.x;
  int n0 = blockIdx.x * 8;
  if (tid < 160) {
    int c = tid >> 3, nl = tid & 7;
    int n = n0 + nl;
    int s = off[n], t = off[n + 1];
    const float* g = gd + (size_t)c * E_EDGES;
    float v = 0.f;
    for (int e = s; e < t; e++) v += g[e];
    ag[nl][c] = v;
    xp[nl][c] = xrp[n * 20 + c];
    if (c == 0) degs[nl] = (float)(t - s);
  }
  __syncthreads();
  if (tid < 8) {
    float v = b1[0] + degs[tid] * b2[0];
#pragma unroll
    for (int c = 0; c < 20; c++) {
      v += ag[tid][c] * W2[c] + xp[tid][c] * W1[c];
    }
    out[n0 + tid] = v;
  }
}

// ---------------- launch ----------------

extern "C" void kernel_launch(void* const* d_in, const int* in_sizes, int n_in,
                              void* d_out, int out_size, void* d_ws, size_t ws_size,
                              hipStream_t stream) {
  const float* features = (const float*)d_in[0];
  const int* edges = (const int*)d_in[1];
  // d_in[2] = weights (unused by reference)

  const float *dW1 = (const float*)d_in[3], *db1 = (const float*)d_in[4],
              *dWm1 = (const float*)d_in[5], *dbm1 = (const float*)d_in[6],
              *dWm2 = (const float*)d_in[7], *dbm2 = (const float*)d_in[8],
              *dW2 = (const float*)d_in[9], *db2 = (const float*)d_in[10];
  const float *hW1 = (const float*)d_in[11], *hb1 = (const float*)d_in[12],
              *hWm1 = (const float*)d_in[13], *hbm1 = (const float*)d_in[14],
              *hWm2 = (const float*)d_in[15], *hbm2 = (const float*)d_in[16],
              *hW2 = (const float*)d_in[17], *hb2 = (const float*)d_in[18];
  const float *oW1 = (const float*)d_in[19], *ob1 = (const float*)d_in[20],
              *oWm1 = (const float*)d_in[21], *obm1 = (const float*)d_in[22],
              *oWm2 = (const float*)d_in[23], *obm2 = (const float*)d_in[24],
              *oW2 = (const float*)d_in[25], *ob2 = (const float*)d_in[26];

  // workspace layout (float units)
  float* fws = (float*)d_ws;
  size_t o = 0;
  float* A2 = fws + o;                    o += (size_t)N_NODES * RS;       // 5.6M
  unsigned char* Bq = (unsigned char*)(fws + o); o += (size_t)N_NODES * RSB / 4;  // 1.6M floats
  float* gd = fws + o;                    o += (size_t)20 * E_EDGES;       // 8.0M ([c][e])
  float* xrA = fws + o;                   o += (size_t)N_NODES * 20;
  float* xrB = fws + o;                   o += (size_t)N_NODES * 20;
  int* ip = (int*)(fws + o);
  int* hist = ip;   ip += N_NODES;
  int* off = ip;    ip += N_NODES + 4;
  int* cursor = ip; ip += N_NODES;
  int2* se = (int2*)ip;

  const int B256 = 256;
  const int EDGE_G = (E_EDGES + B256 - 1) / B256;  // 1563
  const int NODE8_G = N_NODES / 8;  // 3125, exact

  // build dst-sorted edge list + CSR offsets (recomputed every launch)
  (void)hipMemsetAsync(hist, 0, N_NODES * sizeof(int), stream);
  hist_kernel<<<EDGE_G, B256, 0, stream>>>(edges, hist);
  scan_kernel<<<1, 1024, 0, stream>>>(hist, off, cursor);

  // layer d: 1 -> 20 (scatter fused into prep)
  scatter_prep_d_kernel<<<NODE8_G, B256, 0, stream>>>(edges, cursor, se, features,
                                                      dWm1, dbm1, A2, Bq, xrA);
  edge_kernel<1><<<EDGE_G, B256, 0, stream>>>(se, A2, Bq, dWm2, dbm2, gd);
  afp1_kernel<<<NODE8_G, B256, 0, stream>>>(gd, off, xrA, dW1, db1, dW2, db2,
                                            hWm1, hbm1, A2, Bq, xrB);

  // hidden1
  edge_kernel<20><<<EDGE_G, B256, 0, stream>>>(se, A2, Bq, hWm2, hbm2, gd);
  afp20_kernel<<<NODE8_G, B256, 0, stream>>>(gd, off, xrB, hW1, hb1, hW2, hb2,
                                             hWm1, hbm1, A2, Bq, xrA);
  // hidden2
  edge_kernel<20><<<EDGE_G, B256, 0, stream>>>(se, A2, Bq, hWm2, hbm2, gd);
  afp20_kernel<<<NODE8_G, B256, 0, stream>>>(gd, off, xrA, hW1, hb1, hW2, hb2,
                                             hWm1, hbm1, A2, Bq, xrB);
  // hidden3 -> preps output layer (oWm1)
  edge_kernel<20><<<EDGE_G, B256, 0, stream>>>(se, A2, Bq, hWm2, hbm2, gd);
  afp20_kernel<<<NODE8_G, B256, 0, stream>>>(gd, off, xrB, hW1, hb1, hW2, hb2,
                                             oWm1, obm1, A2, Bq, xrA);
  // output layer: 20 -> 1 (no trailing relu)
  edge_kernel<20><<<EDGE_G, B256, 0, stream>>>(se, A2, Bq, oWm2, obm2, gd);
  aggfin_out_kernel<<<NODE8_G, B256, 0, stream>>>(gd, off, xrA, oW1, ob1, oW2, ob2,
                                                  (float*)d_out);
}

// Round 16
// 692.252 us; speedup vs baseline: 6.4341x; 1.1341x over previous
//
#include <hip/hip_runtime.h>
#include <hip/hip_fp16.h>

#define N_NODES 25000   // = 3125 * 8 exactly
#define E_EDGES 400000
#define KM 200      // message channels
#define RS 224      // A-row stride (floats): 200 fp32 A | 20 fp32 x | pad (896 B)
#define RSB 256     // B-row stride BYTES: 200 int8 | pad | 20 fp16 x @208 | inv_p,inv_x @248

__device__ __forceinline__ float2 h2f(unsigned u) {
  return __half22float2(*(const __half2*)&u);
}
__device__ __forceinline__ float4 i8x4f(unsigned u) {
  float4 f;
  f.x = (float)((int)(u << 24) >> 24);
  f.y = (float)((int)(u << 16) >> 24);
  f.z = (float)((int)(u << 8) >> 24);
  f.w = (float)((int)u >> 24);
  return f;
}
// bf16 round-half-up pack / unpack (gd is bf16 to halve its HBM round-trip)
__device__ __forceinline__ unsigned short f2bfr(float v) {
  unsigned u = __float_as_uint(v) + 0x8000u;
  return (unsigned short)(u >> 16);
}
__device__ __forceinline__ float bf2f(unsigned short h) {
  return __uint_as_float((unsigned)h << 16);
}

// ---------------- sort-by-dst (CSR build) ----------------

__global__ void hist_kernel(const int* __restrict__ edges, int* __restrict__ hist) {
  int e = blockIdx.x * blockDim.x + threadIdx.x;
  if (e < E_EDGES) atomicAdd(&hist[edges[E_EDGES + e]], 1);
}

__global__ void scan_kernel(const int* __restrict__ hist, int* __restrict__ off,
                            int* __restrict__ cursor) {
  __shared__ int sums[1024];
  const int CH = (N_NODES + 1023) / 1024;  // 25
  int tid = threadIdx.x;
  int base = tid * CH;
  int s = 0;
  for (int i = 0; i < CH; i++) {
    int idx = base + i;
    if (idx < N_NODES) s += hist[idx];
  }
  sums[tid] = s;
  __syncthreads();
  for (int d = 1; d < 1024; d <<= 1) {
    int v = (tid >= d) ? sums[tid - d] : 0;
    __syncthreads();
    sums[tid] += v;
    __syncthreads();
  }
  int run = (tid == 0) ? 0 : sums[tid - 1];
  for (int i = 0; i < CH; i++) {
    int idx = base + i;
    if (idx < N_NODES) {
      off[idx] = run;
      cursor[idx] = run;
      run += hist[idx];
    }
  }
  if (tid == 1023) off[N_NODES] = run;  // == E
}

// ---------------- per-layer kernels ----------------

// Fused: scatter (128 edges/block) + prep layer-d (8 nodes/block).
// prep: A fp32; B int8 (exact bound: max_k |x*wb_k| = |x|*wbmax); x-tail fp16.
__global__ void __launch_bounds__(256) scatter_prep_d_kernel(
    const int* __restrict__ edges, int* __restrict__ cursor, int2* __restrict__ se,
    const float* __restrict__ xin,
    const float* __restrict__ Wm1, const float* __restrict__ bm1,
    float* __restrict__ A2, unsigned char* __restrict__ Bq, float* __restrict__ xr) {
  int tid = threadIdx.x;
  // scatter part: 3125 * 128 = 400000 exactly
  if (tid < 128) {
    int e = blockIdx.x * 128 + tid;
    int s = edges[e];
    int d = edges[E_EDGES + e];
    int pos = atomicAdd(&cursor[d], 1);
    se[pos] = make_int2(s, d);
  }
  // prep part
  __shared__ unsigned wbmaxu;
  if (tid == 0) wbmaxu = 0;
  __syncthreads();
  int k = tid;
  float wa = 0.f, wb = 0.f, bm = 0.f;
  if (k < KM) {
    bm = bm1[k];
    wa = Wm1[k];
    wb = Wm1[KM + k];
  }
  float mb = (k < KM) ? fabsf(wb) : 0.f;
#pragma unroll
  for (int s = 1; s < 64; s <<= 1) mb = fmaxf(mb, __shfl_xor(mb, s));
  if ((k & 63) == 0) atomicMax(&wbmaxu, __float_as_uint(mb));
  __syncthreads();
  float wbmax = fmaxf(__uint_as_float(wbmaxu), 1e-30f);
  int n0 = blockIdx.x * 8;
  for (int i = 0; i < 8; i++) {
    int n = n0 + i;
    float xv = xin[n];
    float bBound = fmaxf(fabsf(xv) * wbmax, 1e-30f);
    float xBound = fmaxf(fabsf(xv), 1e-30f);
    size_t rowA = (size_t)n * RS;
    unsigned char* rb = Bq + (size_t)n * RSB;
    if (k == 0) {
      xr[n] = xv;
      A2[rowA + KM] = xv;
      ((__half*)(rb + 208))[0] = __float2half(xv * (32768.f / xBound));
      ((float*)(rb + 248))[0] = bBound / 127.f;
      ((float*)(rb + 248))[1] = xBound / 32768.f;
    }
    if (k < KM) {
      A2[rowA + k] = bm + xv * wa;
      rb[k] = (unsigned char)(signed char)lrintf(xv * wb * (127.f / bBound));
    }
  }
}

// Edge kernel: one thread per (dst-sorted) edge, 128-thread blocks (grid 3125 exact).
// A fp32 (dst-shared, streamed), B int8 256 B (randomly gathered).
// h_k = relu(A[dst][k] + B8[src][k]*invB); gate = h@Wm2 + bm2;
// gd layout [c][e] bf16: coalesced nontemporal ushort stores.
template <int CIN>
__global__ void __launch_bounds__(128) edge_kernel(
    const int2* __restrict__ se,
    const float* __restrict__ A2, const unsigned char* __restrict__ Bq,
    const float* __restrict__ Wm2, const float* __restrict__ bm2,
    unsigned short* __restrict__ gd) {
  int e = blockIdx.x * 128 + threadIdx.x;  // grid exact: no bounds check
  int2 sd = se[e];
  int src = sd.x;
  int dst = sd.y;
  const float* Ar = A2 + (size_t)dst * RS;
  const unsigned char* Br = Bq + (size_t)src * RSB;
  float invB = ((const float*)(Br + 248))[0];
  float gate[CIN];
#pragma unroll
  for (int c = 0; c < CIN; c++) gate[c] = bm2[c];
  // main loop: 12 iters of 16 channels (192), then an 8-channel tail
#pragma unroll 2
  for (int k = 0; k < 192; k += 16) {
    float4 a0 = *(const float4*)(Ar + k);
    float4 a1 = *(const float4*)(Ar + k + 4);
    float4 a2 = *(const float4*)(Ar + k + 8);
    float4 a3 = *(const float4*)(Ar + k + 12);
    uint4 braw = *(const uint4*)(Br + k);  // 16 int8
    float4 f0 = i8x4f(braw.x);
    float4 f1 = i8x4f(braw.y);
    float4 f2 = i8x4f(braw.z);
    float4 f3 = i8x4f(braw.w);
    float h[16];
    h[0] = fmaxf(a0.x + f0.x * invB, 0.f);
    h[1] = fmaxf(a0.y + f0.y * invB, 0.f);
    h[2] = fmaxf(a0.z + f0.z * invB, 0.f);
    h[3] = fmaxf(a0.w + f0.w * invB, 0.f);
    h[4] = fmaxf(a1.x + f1.x * invB, 0.f);
    h[5] = fmaxf(a1.y + f1.y * invB, 0.f);
    h[6] = fmaxf(a1.z + f1.z * invB, 0.f);
    h[7] = fmaxf(a1.w + f1.w * invB, 0.f);
    h[8] = fmaxf(a2.x + f2.x * invB, 0.f);
    h[9] = fmaxf(a2.y + f2.y * invB, 0.f);
    h[10] = fmaxf(a2.z + f2.z * invB, 0.f);
    h[11] = fmaxf(a2.w + f2.w * invB, 0.f);
    h[12] = fmaxf(a3.x + f3.x * invB, 0.f);
    h[13] = fmaxf(a3.y + f3.y * invB, 0.f);
    h[14] = fmaxf(a3.z + f3.z * invB, 0.f);
    h[15] = fmaxf(a3.w + f3.w * invB, 0.f);
#pragma unroll
    for (int c = 0; c < CIN; c++) {
      float g = gate[c];
#pragma unroll
      for (int j = 0; j < 16; j++) g += h[j] * Wm2[(k + j) * CIN + c];
      gate[c] = g;
    }
  }
  {  // tail k = 192..199
    float4 a0 = *(const float4*)(Ar + 192);
    float4 a1 = *(const float4*)(Ar + 196);
    uint2 braw = *(const uint2*)(Br + 192);
    float4 f01 = i8x4f(braw.x);
    float4 f23 = i8x4f(braw.y);
    float h[8];
    h[0] = fmaxf(a0.x + f01.x * invB, 0.f);
    h[1] = fmaxf(a0.y + f01.y * invB, 0.f);
    h[2] = fmaxf(a0.z + f01.z * invB, 0.f);
    h[3] = fmaxf(a0.w + f01.w * invB, 0.f);
    h[4] = fmaxf(a1.x + f23.x * invB, 0.f);
    h[5] = fmaxf(a1.y + f23.y * invB, 0.f);
    h[6] = fmaxf(a1.z + f23.z * invB, 0.f);
    h[7] = fmaxf(a1.w + f23.w * invB, 0.f);
#pragma unroll
    for (int c = 0; c < CIN; c++) {
      float g = gate[c];
#pragma unroll
      for (int j = 0; j < 8; j++) g += h[j] * Wm2[(192 + j) * CIN + c];
      gate[c] = g;
    }
  }
  // x-diff tails: A fp32, B fp16-scaled; coalesced nontemporal bf16 stores
  float invXb = ((const float*)(Br + 248))[1];
  const __half* xtb = (const __half*)(Br + 208);
  if constexpr (CIN == 20) {
    unsigned wxb[10];
    {
      uint4 s0 = *(const uint4*)(xtb);
      uint4 s1 = *(const uint4*)(xtb + 8);
      uint2 s2 = *(const uint2*)(xtb + 16);
      wxb[0] = s0.x; wxb[1] = s0.y; wxb[2] = s0.z; wxb[3] = s0.w;
      wxb[4] = s1.x; wxb[5] = s1.y; wxb[6] = s1.z; wxb[7] = s1.w;
      wxb[8] = s2.x; wxb[9] = s2.y;
    }
#pragma unroll
    for (int i = 0; i < 10; i++) {
      float2 xa = *(const float2*)(Ar + KM + 2 * i);
      float2 fb = h2f(wxb[i]);
      int c0 = 2 * i, c1 = 2 * i + 1;
      __builtin_nontemporal_store(f2bfr(gate[c0] * (xa.x - fb.x * invXb)),
                                  gd + (size_t)c0 * E_EDGES + e);
      __builtin_nontemporal_store(f2bfr(gate[c1] * (xa.y - fb.y * invXb)),
                                  gd + (size_t)c1 * E_EDGES + e);
    }
  } else {
    float xa = Ar[KM];
    float xb = __half2float(xtb[0]) * invXb;
    __builtin_nontemporal_store(f2bfr(gate[0] * (xa - xb)), gd + e);
  }
}

// afp1: after layer-d edge (gd 1-channel bf16). Per block: 8 nodes.
__global__ void __launch_bounds__(256) afp1_kernel(
    const unsigned short* __restrict__ gd, const int* __restrict__ off,
    const float* __restrict__ xrp,
    const float* __restrict__ W1, const float* __restrict__ b1,
    const float* __restrict__ W2, const float* __restrict__ b2,
    const float* __restrict__ Wm1n, const float* __restrict__ bm1n,
    float* __restrict__ A2, unsigned char* __restrict__ Bq, float* __restrict__ xrn) {
  __shared__ float ag[8], xp[8], degs[8];
  __shared__ float xv[8][21];
  __shared__ unsigned bmaxu[8];
  __shared__ float xmaxs[8];
  int tid = threadIdx.x;
  int n0 = blockIdx.x * 8;
  if (tid < 8) {
    bmaxu[tid] = 0;
    int n = n0 + tid;
    int s = off[n], t = off[n + 1];
    float v = 0.f;
    for (int e = s; e < t; e++) v += bf2f(gd[e]);
    ag[tid] = v;
    xp[tid] = xrp[n];
    degs[tid] = (float)(t - s);
  }
  __syncthreads();
  if (tid < 160) {
    int o = tid >> 3, nl = tid & 7;
    float v = b1[o] + degs[nl] * b2[o] + ag[nl] * W2[o] + xp[nl] * W1[o];
    float r = fmaxf(v, 0.f);
    xv[nl][o] = r;
    xrn[(n0 + nl) * 20 + o] = r;
  }
  __syncthreads();
  if (tid < 8) {
    float m = 0.f;
#pragma unroll
    for (int c = 0; c < 20; c++) m = fmaxf(m, xv[tid][c]);
    xmaxs[tid] = fmaxf(m, 1e-30f);
  }
  int k = tid;
  float aa[8], bb[8];
  if (k < KM) {
    float wa[20], wb[20];
    float bm = bm1n[k];
#pragma unroll
    for (int c = 0; c < 20; c++) {
      wa[c] = Wm1n[c * KM + k];
      wb[c] = Wm1n[(20 + c) * KM + k];
    }
#pragma unroll
    for (int nl = 0; nl < 8; nl++) {
      float a = bm, b = 0.f;
#pragma unroll
      for (int c = 0; c < 20; c++) {
        a += xv[nl][c] * wa[c];
        b += xv[nl][c] * wb[c];
      }
      aa[nl] = a;
      bb[nl] = b;
    }
  }
  float mxb[8];
#pragma unroll
  for (int nl = 0; nl < 8; nl++) mxb[nl] = (k < KM) ? fabsf(bb[nl]) : 0.f;
#pragma unroll
  for (int s = 1; s < 64; s <<= 1) {
#pragma unroll
    for (int nl = 0; nl < 8; nl++) mxb[nl] = fmaxf(mxb[nl], __shfl_xor(mxb[nl], s));
  }
  if ((tid & 63) == 0) {
#pragma unroll
    for (int nl = 0; nl < 8; nl++) atomicMax(&bmaxu[nl], __float_as_uint(mxb[nl]));
  }
  __syncthreads();
  if (k < KM) {
#pragma unroll
    for (int nl = 0; nl < 8; nl++) {
      float bmax = fmaxf(__uint_as_float(bmaxu[nl]), 1e-30f);
      float xmax = xmaxs[nl];
      size_t rowA = (size_t)(n0 + nl) * RS;
      unsigned char* rb = Bq + (size_t)(n0 + nl) * RSB;
      A2[rowA + k] = aa[nl];
      rb[k] = (unsigned char)(signed char)lrintf(bb[nl] * (127.f / bmax));
      if (k < 20) {
        A2[rowA + KM + k] = xv[nl][k];
        ((__half*)(rb + 208))[k] = __float2half(xv[nl][k] * (32768.f / xmax));
      }
      if (k == 0) {
        ((float*)(rb + 248))[0] = bmax / 127.f;
        ((float*)(rb + 248))[1] = xmax / 32768.f;
      }
    }
  }
}

// afp20: after a hidden edge (gd 20-channel bf16). Same 3 phases, CIN=20.
__global__ void __launch_bounds__(256) afp20_kernel(
    const unsigned short* __restrict__ gd, const int* __restrict__ off,
    const float* __restrict__ xrp,
    const float* __restrict__ W1, const float* __restrict__ b1,
    const float* __restrict__ W2, const float* __restrict__ b2,
    const float* __restrict__ Wm1n, const float* __restrict__ bm1n,
    float* __restrict__ A2, unsigned char* __restrict__ Bq, float* __restrict__ xrn) {
  __shared__ float ag[8][21], xp[8][21], xv[8][21], degs[8];
  __shared__ unsigned bmaxu[8];
  __shared__ float xmaxs[8];
  int tid = threadIdx.x;
  int n0 = blockIdx.x * 8;
  if (tid < 8) bmaxu[tid] = 0;
  if (tid < 160) {
    int c = tid >> 3, nl = tid & 7;  // adjacent lanes: same c, adjacent n
    int n = n0 + nl;
    int s = off[n], t = off[n + 1];
    const unsigned short* g = gd + (size_t)c * E_EDGES;
    float v = 0.f;
    for (int e = s; e < t; e++) v += bf2f(g[e]);
    ag[nl][c] = v;
    xp[nl][c] = xrp[n * 20 + c];
    if (c == 0) degs[nl] = (float)(t - s);
  }
  __syncthreads();
  if (tid < 160) {
    int o = tid >> 3, nl = tid & 7;
    float v = b1[o] + degs[nl] * b2[o];
#pragma unroll
    for (int c = 0; c < 20; c++) {
      v += ag[nl][c] * W2[c * 20 + o] + xp[nl][c] * W1[c * 20 + o];
    }
    float r = fmaxf(v, 0.f);
    xv[nl][o] = r;
    xrn[(n0 + nl) * 20 + o] = r;
  }
  __syncthreads();
  if (tid < 8) {
    float m = 0.f;
#pragma unroll
    for (int c = 0; c < 20; c++) m = fmaxf(m, xv[tid][c]);
    xmaxs[tid] = fmaxf(m, 1e-30f);
  }
  int k = tid;
  float aa[8], bb[8];
  if (k < KM) {
    float wa[20], wb[20];
    float bm = bm1n[k];
#pragma unroll
    for (int c = 0; c < 20; c++) {
      wa[c] = Wm1n[c * KM + k];
      wb[c] = Wm1n[(20 + c) * KM + k];
    }
#pragma unroll
    for (int nl = 0; nl < 8; nl++) {
      float a = bm, b = 0.f;
#pragma unroll
      for (int c = 0; c < 20; c++) {
        a += xv[nl][c] * wa[c];
        b += xv[nl][c] * wb[c];
      }
      aa[nl] = a;
      bb[nl] = b;
    }
  }
  float mxb[8];
#pragma unroll
  for (int nl = 0; nl < 8; nl++) mxb[nl] = (k < KM) ? fabsf(bb[nl]) : 0.f;
#pragma unroll
  for (int s = 1; s < 64; s <<= 1) {
#pragma unroll
    for (int nl = 0; nl < 8; nl++) mxb[nl] = fmaxf(mxb[nl], __shfl_xor(mxb[nl], s));
  }
  if ((tid & 63) == 0) {
#pragma unroll
    for (int nl = 0; nl < 8; nl++) atomicMax(&bmaxu[nl], __float_as_uint(mxb[nl]));
  }
  __syncthreads();
  if (k < KM) {
#pragma unroll
    for (int nl = 0; nl < 8; nl++) {
      float bmax = fmaxf(__uint_as_float(bmaxu[nl]), 1e-30f);
      float xmax = xmaxs[nl];
      size_t rowA = (size_t)(n0 + nl) * RS;
      unsigned char* rb = Bq + (size_t)(n0 + nl) * RSB;
      A2[rowA + k] = aa[nl];
      rb[k] = (unsigned char)(signed char)lrintf(bb[nl] * (127.f / bmax));
      if (k < 20) {
        A2[rowA + KM + k] = xv[nl][k];
        ((__half*)(rb + 208))[k] = __float2half(xv[nl][k] * (32768.f / xmax));
      }
      if (k == 0) {
        ((float*)(rb + 248))[0] = bmax / 127.f;
        ((float*)(rb + 248))[1] = xmax / 32768.f;
      }
    }
  }
}

// final: agg(20ch bf16) + fin(20->1), no relu, writes d_out.
__global__ void __launch_bounds__(256) aggfin_out_kernel(
    const unsigned short* __restrict__ gd, const int* __restrict__ off,
    const float* __restrict__ xrp,
    const float* __restrict__ W1, const float* __restrict__ b1,
    const float* __restrict__ W2, const float* __restrict__ b2,
    float* __restrict__ out) {
  __shared__ float ag[8][21], xp[8][21], degs[8];
  int tid = threadIdx.x;
  int n0 = blockIdx.x * 8;
  if (tid < 160) {
    int c = tid >> 3, nl = tid & 7;
    int n = n0 + nl;
    int s = off[n], t = off[n + 1];
    const unsigned short* g = gd + (size_t)c * E_EDGES;
    float v = 0.f;
    for (int e = s; e < t; e++) v += bf2f(g[e]);
    ag[nl][c] = v;
    xp[nl][c] = xrp[n * 20 + c];
    if (c == 0) degs[nl] = (float)(t - s);
  }
  __syncthreads();
  if (tid < 8) {
    float v = b1[0] + degs[tid] * b2[0];
#pragma unroll
    for (int c = 0; c < 20; c++) {
      v += ag[tid][c] * W2[c] + xp[tid][c] * W1[c];
    }
    out[n0 + tid] = v;
  }
}

// ---------------- launch ----------------

extern "C" void kernel_launch(void* const* d_in, const int* in_sizes, int n_in,
                              void* d_out, int out_size, void* d_ws, size_t ws_size,
                              hipStream_t stream) {
  const float* features = (const float*)d_in[0];
  const int* edges = (const int*)d_in[1];
  // d_in[2] = weights (unused by reference)

  const float *dW1 = (const float*)d_in[3], *db1 = (const float*)d_in[4],
              *dWm1 = (const float*)d_in[5], *dbm1 = (const float*)d_in[6],
              *dWm2 = (const float*)d_in[7], *dbm2 = (const float*)d_in[8],
              *dW2 = (const float*)d_in[9], *db2 = (const float*)d_in[10];
  const float *hW1 = (const float*)d_in[11], *hb1 = (const float*)d_in[12],
              *hWm1 = (const float*)d_in[13], *hbm1 = (const float*)d_in[14],
              *hWm2 = (const float*)d_in[15], *hbm2 = (const float*)d_in[16],
              *hW2 = (const float*)d_in[17], *hb2 = (const float*)d_in[18];
  const float *oW1 = (const float*)d_in[19], *ob1 = (const float*)d_in[20],
              *oWm1 = (const float*)d_in[21], *obm1 = (const float*)d_in[22],
              *oWm2 = (const float*)d_in[23], *obm2 = (const float*)d_in[24],
              *oW2 = (const float*)d_in[25], *ob2 = (const float*)d_in[26];

  // workspace layout (float units)
  float* fws = (float*)d_ws;
  size_t o = 0;
  float* A2 = fws + o;                           o += (size_t)N_NODES * RS;       // 5.6M
  unsigned char* Bq = (unsigned char*)(fws + o); o += (size_t)N_NODES * RSB / 4;  // 1.6M floats
  unsigned short* gd = (unsigned short*)(fws + o); o += (size_t)20 * E_EDGES / 2; // 4.0M floats (bf16)
  float* xrA = fws + o;                          o += (size_t)N_NODES * 20;
  float* xrB = fws + o;                          o += (size_t)N_NODES * 20;
  int* ip = (int*)(fws + o);
  int* hist = ip;   ip += N_NODES;
  int* off = ip;    ip += N_NODES + 4;
  int* cursor = ip; ip += N_NODES;
  int2* se = (int2*)ip;

  const int B256 = 256;
  const int EDGE_G = E_EDGES / 128;  // 3125, exact (128-thread blocks)
  const int NODE8_G = N_NODES / 8;   // 3125, exact

  // build dst-sorted edge list + CSR offsets (recomputed every launch)
  (void)hipMemsetAsync(hist, 0, N_NODES * sizeof(int), stream);
  hist_kernel<<<(E_EDGES + B256 - 1) / B256, B256, 0, stream>>>(edges, hist);
  scan_kernel<<<1, 1024, 0, stream>>>(hist, off, cursor);

  // layer d: 1 -> 20 (scatter fused into prep)
  scatter_prep_d_kernel<<<NODE8_G, B256, 0, stream>>>(edges, cursor, se, features,
                                                      dWm1, dbm1, A2, Bq, xrA);
  edge_kernel<1><<<EDGE_G, 128, 0, stream>>>(se, A2, Bq, dWm2, dbm2, gd);
  afp1_kernel<<<NODE8_G, B256, 0, stream>>>(gd, off, xrA, dW1, db1, dW2, db2,
                                            hWm1, hbm1, A2, Bq, xrB);

  // hidden1
  edge_kernel<20><<<EDGE_G, 128, 0, stream>>>(se, A2, Bq, hWm2, hbm2, gd);
  afp20_kernel<<<NODE8_G, B256, 0, stream>>>(gd, off, xrB, hW1, hb1, hW2, hb2,
                                             hWm1, hbm1, A2, Bq, xrA);
  // hidden2
  edge_kernel<20><<<EDGE_G, 128, 0, stream>>>(se, A2, Bq, hWm2, hbm2, gd);
  afp20_kernel<<<NODE8_G, B256, 0, stream>>>(gd, off, xrA, hW1, hb1, hW2, hb2,
                                             hWm1, hbm1, A2, Bq, xrB);
  // hidden3 -> preps output layer (oWm1)
  edge_kernel<20><<<EDGE_G, 128, 0, stream>>>(se, A2, Bq, hWm2, hbm2, gd);
  afp20_kernel<<<NODE8_G, B256, 0, stream>>>(gd, off, xrB, hW1, hb1, hW2, hb2,
                                             oWm1, obm1, A2, Bq, xrA);
  // output layer: 20 -> 1 (no trailing relu)
  edge_kernel<20><<<EDGE_G, 128, 0, stream>>>(se, A2, Bq, oWm2, obm2, gd);
  aggfin_out_kernel<<<NODE8_G, B256, 0, stream>>>(gd, off, xrA, oW1, ob1, oW2, ob2,
                                                  (float*)d_out);
}

// Round 17
// 660.537 us; speedup vs baseline: 6.7430x; 1.0480x over previous
//
#include <hip/hip_runtime.h>
#include <hip/hip_fp16.h>

#define N_NODES 25000   // = 3125 * 8 exactly
#define E_EDGES 400000
#define KM 200      // message channels
#define RS 224      // A-row stride (floats): 200 fp32 A | 20 fp32 x | pad (896 B)
#define RSB 256     // B-row stride BYTES: 200 int8 | pad | 20 fp16 x @208 | inv_p,inv_x @248

typedef float v2f __attribute__((ext_vector_type(2)));  // v_pk_fma_f32 operand

__device__ __forceinline__ float2 h2f(unsigned u) {
  return __half22float2(*(const __half2*)&u);
}
__device__ __forceinline__ float4 i8x4f(unsigned u) {
  float4 f;
  f.x = (float)((int)(u << 24) >> 24);
  f.y = (float)((int)(u << 16) >> 24);
  f.z = (float)((int)(u << 8) >> 24);
  f.w = (float)((int)u >> 24);
  return f;
}
// bf16 round-half-up pack / unpack (gd is bf16 to halve its HBM round-trip)
__device__ __forceinline__ unsigned short f2bfr(float v) {
  unsigned u = __float_as_uint(v) + 0x8000u;
  return (unsigned short)(u >> 16);
}
__device__ __forceinline__ float bf2f(unsigned short h) {
  return __uint_as_float((unsigned)h << 16);
}

// ---------------- sort-by-dst (CSR build) ----------------

__global__ void hist_kernel(const int* __restrict__ edges, int* __restrict__ hist) {
  int e = blockIdx.x * blockDim.x + threadIdx.x;
  if (e < E_EDGES) atomicAdd(&hist[edges[E_EDGES + e]], 1);
}

__global__ void scan_kernel(const int* __restrict__ hist, int* __restrict__ off,
                            int* __restrict__ cursor) {
  __shared__ int sums[1024];
  const int CH = (N_NODES + 1023) / 1024;  // 25
  int tid = threadIdx.x;
  int base = tid * CH;
  int s = 0;
  for (int i = 0; i < CH; i++) {
    int idx = base + i;
    if (idx < N_NODES) s += hist[idx];
  }
  sums[tid] = s;
  __syncthreads();
  for (int d = 1; d < 1024; d <<= 1) {
    int v = (tid >= d) ? sums[tid - d] : 0;
    __syncthreads();
    sums[tid] += v;
    __syncthreads();
  }
  int run = (tid == 0) ? 0 : sums[tid - 1];
  for (int i = 0; i < CH; i++) {
    int idx = base + i;
    if (idx < N_NODES) {
      off[idx] = run;
      cursor[idx] = run;
      run += hist[idx];
    }
  }
  if (tid == 1023) off[N_NODES] = run;  // == E
}

// ---------------- per-layer kernels ----------------

// Fused: scatter (128 edges/block) + prep layer-d (8 nodes/block).
// prep: A fp32; B int8 (exact bound: max_k |x*wb_k| = |x|*wbmax); x-tail fp16.
__global__ void __launch_bounds__(256) scatter_prep_d_kernel(
    const int* __restrict__ edges, int* __restrict__ cursor, int2* __restrict__ se,
    const float* __restrict__ xin,
    const float* __restrict__ Wm1, const float* __restrict__ bm1,
    float* __restrict__ A2, unsigned char* __restrict__ Bq, float* __restrict__ xr) {
  int tid = threadIdx.x;
  // scatter part: 3125 * 128 = 400000 exactly
  if (tid < 128) {
    int e = blockIdx.x * 128 + tid;
    int s = edges[e];
    int d = edges[E_EDGES + e];
    int pos = atomicAdd(&cursor[d], 1);
    se[pos] = make_int2(s, d);
  }
  // prep part
  __shared__ unsigned wbmaxu;
  if (tid == 0) wbmaxu = 0;
  __syncthreads();
  int k = tid;
  float wa = 0.f, wb = 0.f, bm = 0.f;
  if (k < KM) {
    bm = bm1[k];
    wa = Wm1[k];
    wb = Wm1[KM + k];
  }
  float mb = (k < KM) ? fabsf(wb) : 0.f;
#pragma unroll
  for (int s = 1; s < 64; s <<= 1) mb = fmaxf(mb, __shfl_xor(mb, s));
  if ((k & 63) == 0) atomicMax(&wbmaxu, __float_as_uint(mb));
  __syncthreads();
  float wbmax = fmaxf(__uint_as_float(wbmaxu), 1e-30f);
  int n0 = blockIdx.x * 8;
  for (int i = 0; i < 8; i++) {
    int n = n0 + i;
    float xv = xin[n];
    float bBound = fmaxf(fabsf(xv) * wbmax, 1e-30f);
    float xBound = fmaxf(fabsf(xv), 1e-30f);
    size_t rowA = (size_t)n * RS;
    unsigned char* rb = Bq + (size_t)n * RSB;
    if (k == 0) {
      xr[n] = xv;
      A2[rowA + KM] = xv;
      ((__half*)(rb + 208))[0] = __float2half(xv * (32768.f / xBound));
      ((float*)(rb + 248))[0] = bBound / 127.f;
      ((float*)(rb + 248))[1] = xBound / 32768.f;
    }
    if (k < KM) {
      A2[rowA + k] = bm + xv * wa;
      rb[k] = (unsigned char)(signed char)lrintf(xv * wb * (127.f / bBound));
    }
  }
}

// Edge kernel: one thread per (dst-sorted) edge, 128-thread blocks (grid 3125 exact).
// A fp32 (dst-shared, streamed), B int8 256 B (randomly gathered).
// h_k = relu(A[dst][k] + B8[src][k]*invB); gate = h@Wm2 + bm2 via packed f32
// (v_pk_fma_f32 — gate/Wm2 channel pairs are contiguous); gd [c][e] bf16 nt-stores.
template <int CIN>
__global__ void __launch_bounds__(128) edge_kernel(
    const int2* __restrict__ se,
    const float* __restrict__ A2, const unsigned char* __restrict__ Bq,
    const float* __restrict__ Wm2, const float* __restrict__ bm2,
    unsigned short* __restrict__ gd) {
  int e = blockIdx.x * 128 + threadIdx.x;  // grid exact: no bounds check
  int2 sd = se[e];
  int src = sd.x;
  int dst = sd.y;
  const float* Ar = A2 + (size_t)dst * RS;
  const unsigned char* Br = Bq + (size_t)src * RSB;
  float invB = ((const float*)(Br + 248))[0];
  constexpr int NP = (CIN + 1) / 2;
  v2f gate2[NP];
  if constexpr (CIN == 20) {
#pragma unroll
    for (int i = 0; i < NP; i++) gate2[i] = *(const v2f*)(bm2 + 2 * i);
  } else {
    gate2[0].x = bm2[0];
    gate2[0].y = 0.f;
  }
  // main loop: 12 iters of 16 channels (192), then an 8-channel tail
#pragma unroll 2
  for (int k = 0; k < 192; k += 16) {
    float4 a0 = *(const float4*)(Ar + k);
    float4 a1 = *(const float4*)(Ar + k + 4);
    float4 a2 = *(const float4*)(Ar + k + 8);
    float4 a3 = *(const float4*)(Ar + k + 12);
    uint4 braw = *(const uint4*)(Br + k);  // 16 int8
    float4 f0 = i8x4f(braw.x);
    float4 f1 = i8x4f(braw.y);
    float4 f2 = i8x4f(braw.z);
    float4 f3 = i8x4f(braw.w);
    float h[16];
    h[0] = fmaxf(a0.x + f0.x * invB, 0.f);
    h[1] = fmaxf(a0.y + f0.y * invB, 0.f);
    h[2] = fmaxf(a0.z + f0.z * invB, 0.f);
    h[3] = fmaxf(a0.w + f0.w * invB, 0.f);
    h[4] = fmaxf(a1.x + f1.x * invB, 0.f);
    h[5] = fmaxf(a1.y + f1.y * invB, 0.f);
    h[6] = fmaxf(a1.z + f1.z * invB, 0.f);
    h[7] = fmaxf(a1.w + f1.w * invB, 0.f);
    h[8] = fmaxf(a2.x + f2.x * invB, 0.f);
    h[9] = fmaxf(a2.y + f2.y * invB, 0.f);
    h[10] = fmaxf(a2.z + f2.z * invB, 0.f);
    h[11] = fmaxf(a2.w + f2.w * invB, 0.f);
    h[12] = fmaxf(a3.x + f3.x * invB, 0.f);
    h[13] = fmaxf(a3.y + f3.y * invB, 0.f);
    h[14] = fmaxf(a3.z + f3.z * invB, 0.f);
    h[15] = fmaxf(a3.w + f3.w * invB, 0.f);
    if constexpr (CIN == 20) {
#pragma unroll
      for (int j = 0; j < 16; j++) {
        v2f hj;
        hj.x = h[j];
        hj.y = h[j];
        const v2f* w2 = (const v2f*)(Wm2 + (k + j) * 20);
#pragma unroll
        for (int i = 0; i < 10; i++) gate2[i] += hj * w2[i];
      }
    } else {
      float g = gate2[0].x;
#pragma unroll
      for (int j = 0; j < 16; j++) g += h[j] * Wm2[k + j];
      gate2[0].x = g;
    }
  }
  {  // tail k = 192..199
    float4 a0 = *(const float4*)(Ar + 192);
    float4 a1 = *(const float4*)(Ar + 196);
    uint2 braw = *(const uint2*)(Br + 192);
    float4 f01 = i8x4f(braw.x);
    float4 f23 = i8x4f(braw.y);
    float h[8];
    h[0] = fmaxf(a0.x + f01.x * invB, 0.f);
    h[1] = fmaxf(a0.y + f01.y * invB, 0.f);
    h[2] = fmaxf(a0.z + f01.z * invB, 0.f);
    h[3] = fmaxf(a0.w + f01.w * invB, 0.f);
    h[4] = fmaxf(a1.x + f23.x * invB, 0.f);
    h[5] = fmaxf(a1.y + f23.y * invB, 0.f);
    h[6] = fmaxf(a1.z + f23.z * invB, 0.f);
    h[7] = fmaxf(a1.w + f23.w * invB, 0.f);
    if constexpr (CIN == 20) {
#pragma unroll
      for (int j = 0; j < 8; j++) {
        v2f hj;
        hj.x = h[j];
        hj.y = h[j];
        const v2f* w2 = (const v2f*)(Wm2 + (192 + j) * 20);
#pragma unroll
        for (int i = 0; i < 10; i++) gate2[i] += hj * w2[i];
      }
    } else {
      float g = gate2[0].x;
#pragma unroll
      for (int j = 0; j < 8; j++) g += h[j] * Wm2[192 + j];
      gate2[0].x = g;
    }
  }
  // x-diff tails: A fp32, B fp16-scaled; coalesced nontemporal bf16 stores
  float invXb = ((const float*)(Br + 248))[1];
  const __half* xtb = (const __half*)(Br + 208);
  if constexpr (CIN == 20) {
    unsigned wxb[10];
    {
      uint4 s0 = *(const uint4*)(xtb);
      uint4 s1 = *(const uint4*)(xtb + 8);
      uint2 s2 = *(const uint2*)(xtb + 16);
      wxb[0] = s0.x; wxb[1] = s0.y; wxb[2] = s0.z; wxb[3] = s0.w;
      wxb[4] = s1.x; wxb[5] = s1.y; wxb[6] = s1.z; wxb[7] = s1.w;
      wxb[8] = s2.x; wxb[9] = s2.y;
    }
#pragma unroll
    for (int i = 0; i < 10; i++) {
      float2 xa = *(const float2*)(Ar + KM + 2 * i);
      float2 fb = h2f(wxb[i]);
      int c0 = 2 * i, c1 = 2 * i + 1;
      __builtin_nontemporal_store(f2bfr(gate2[i].x * (xa.x - fb.x * invXb)),
                                  gd + (size_t)c0 * E_EDGES + e);
      __builtin_nontemporal_store(f2bfr(gate2[i].y * (xa.y - fb.y * invXb)),
                                  gd + (size_t)c1 * E_EDGES + e);
    }
  } else {
    float xa = Ar[KM];
    float xb = __half2float(xtb[0]) * invXb;
    __builtin_nontemporal_store(f2bfr(gate2[0].x * (xa - xb)), gd + e);
  }
}

// afp1: after layer-d edge (gd 1-channel bf16). Per block: 8 nodes.
__global__ void __launch_bounds__(256) afp1_kernel(
    const unsigned short* __restrict__ gd, const int* __restrict__ off,
    const float* __restrict__ xrp,
    const float* __restrict__ W1, const float* __restrict__ b1,
    const float* __restrict__ W2, const float* __restrict__ b2,
    const float* __restrict__ Wm1n, const float* __restrict__ bm1n,
    float* __restrict__ A2, unsigned char* __restrict__ Bq, float* __restrict__ xrn) {
  __shared__ float ag[8], xp[8], degs[8];
  __shared__ float xv[8][21];
  __shared__ unsigned bmaxu[8];
  __shared__ float xmaxs[8];
  int tid = threadIdx.x;
  int n0 = blockIdx.x * 8;
  if (tid < 8) {
    bmaxu[tid] = 0;
    int n = n0 + tid;
    int s = off[n], t = off[n + 1];
    float v = 0.f;
    for (int e = s; e < t; e++) v += bf2f(gd[e]);
    ag[tid] = v;
    xp[tid] = xrp[n];
    degs[tid] = (float)(t - s);
  }
  __syncthreads();
  if (tid < 160) {
    int o = tid >> 3, nl = tid & 7;
    float v = b1[o] + degs[nl] * b2[o] + ag[nl] * W2[o] + xp[nl] * W1[o];
    float r = fmaxf(v, 0.f);
    xv[nl][o] = r;
    xrn[(n0 + nl) * 20 + o] = r;
  }
  __syncthreads();
  if (tid < 8) {
    float m = 0.f;
#pragma unroll
    for (int c = 0; c < 20; c++) m = fmaxf(m, xv[tid][c]);
    xmaxs[tid] = fmaxf(m, 1e-30f);
  }
  int k = tid;
  float aa[8], bb[8];
  if (k < KM) {
    float wa[20], wb[20];
    float bm = bm1n[k];
#pragma unroll
    for (int c = 0; c < 20; c++) {
      wa[c] = Wm1n[c * KM + k];
      wb[c] = Wm1n[(20 + c) * KM + k];
    }
#pragma unroll
    for (int nl = 0; nl < 8; nl++) {
      float a = bm, b = 0.f;
#pragma unroll
      for (int c = 0; c < 20; c++) {
        a += xv[nl][c] * wa[c];
        b += xv[nl][c] * wb[c];
      }
      aa[nl] = a;
      bb[nl] = b;
    }
  }
  float mxb[8];
#pragma unroll
  for (int nl = 0; nl < 8; nl++) mxb[nl] = (k < KM) ? fabsf(bb[nl]) : 0.f;
#pragma unroll
  for (int s = 1; s < 64; s <<= 1) {
#pragma unroll
    for (int nl = 0; nl < 8; nl++) mxb[nl] = fmaxf(mxb[nl], __shfl_xor(mxb[nl], s));
  }
  if ((tid & 63) == 0) {
#pragma unroll
    for (int nl = 0; nl < 8; nl++) atomicMax(&bmaxu[nl], __float_as_uint(mxb[nl]));
  }
  __syncthreads();
  if (k < KM) {
#pragma unroll
    for (int nl = 0; nl < 8; nl++) {
      float bmax = fmaxf(__uint_as_float(bmaxu[nl]), 1e-30f);
      float xmax = xmaxs[nl];
      size_t rowA = (size_t)(n0 + nl) * RS;
      unsigned char* rb = Bq + (size_t)(n0 + nl) * RSB;
      A2[rowA + k] = aa[nl];
      rb[k] = (unsigned char)(signed char)lrintf(bb[nl] * (127.f / bmax));
      if (k < 20) {
        A2[rowA + KM + k] = xv[nl][k];
        ((__half*)(rb + 208))[k] = __float2half(xv[nl][k] * (32768.f / xmax));
      }
      if (k == 0) {
        ((float*)(rb + 248))[0] = bmax / 127.f;
        ((float*)(rb + 248))[1] = xmax / 32768.f;
      }
    }
  }
}

// afp20: after a hidden edge (gd 20-channel bf16). Same 3 phases, CIN=20.
__global__ void __launch_bounds__(256) afp20_kernel(
    const unsigned short* __restrict__ gd, const int* __restrict__ off,
    const float* __restrict__ xrp,
    const float* __restrict__ W1, const float* __restrict__ b1,
    const float* __restrict__ W2, const float* __restrict__ b2,
    const float* __restrict__ Wm1n, const float* __restrict__ bm1n,
    float* __restrict__ A2, unsigned char* __restrict__ Bq, float* __restrict__ xrn) {
  __shared__ float ag[8][21], xp[8][21], xv[8][21], degs[8];
  __shared__ unsigned bmaxu[8];
  __shared__ float xmaxs[8];
  int tid = threadIdx.x;
  int n0 = blockIdx.x * 8;
  if (tid < 8) bmaxu[tid] = 0;
  if (tid < 160) {
    int c = tid >> 3, nl = tid & 7;  // adjacent lanes: same c, adjacent n
    int n = n0 + nl;
    int s = off[n], t = off[n + 1];
    const unsigned short* g = gd + (size_t)c * E_EDGES;
    float v = 0.f;
    for (int e = s; e < t; e++) v += bf2f(g[e]);
    ag[nl][c] = v;
    xp[nl][c] = xrp[n * 20 + c];
    if (c == 0) degs[nl] = (float)(t - s);
  }
  __syncthreads();
  if (tid < 160) {
    int o = tid >> 3, nl = tid & 7;
    float v = b1[o] + degs[nl] * b2[o];
#pragma unroll
    for (int c = 0; c < 20; c++) {
      v += ag[nl][c] * W2[c * 20 + o] + xp[nl][c] * W1[c * 20 + o];
    }
    float r = fmaxf(v, 0.f);
    xv[nl][o] = r;
    xrn[(n0 + nl) * 20 + o] = r;
  }
  __syncthreads();
  if (tid < 8) {
    float m = 0.f;
#pragma unroll
    for (int c = 0; c < 20; c++) m = fmaxf(m, xv[tid][c]);
    xmaxs[tid] = fmaxf(m, 1e-30f);
  }
  int k = tid;
  float aa[8], bb[8];
  if (k < KM) {
    float wa[20], wb[20];
    float bm = bm1n[k];
#pragma unroll
    for (int c = 0; c < 20; c++) {
      wa[c] = Wm1n[c * KM + k];
      wb[c] = Wm1n[(20 + c) * KM + k];
    }
#pragma unroll
    for (int nl = 0; nl < 8; nl++) {
      float a = bm, b = 0.f;
#pragma unroll
      for (int c = 0; c < 20; c++) {
        a += xv[nl][c] * wa[c];
        b += xv[nl][c] * wb[c];
      }
      aa[nl] = a;
      bb[nl] = b;
    }
  }
  float mxb[8];
#pragma unroll
  for (int nl = 0; nl < 8; nl++) mxb[nl] = (k < KM) ? fabsf(bb[nl]) : 0.f;
#pragma unroll
  for (int s = 1; s < 64; s <<= 1) {
#pragma unroll
    for (int nl = 0; nl < 8; nl++) mxb[nl] = fmaxf(mxb[nl], __shfl_xor(mxb[nl], s));
  }
  if ((tid & 63) == 0) {
#pragma unroll
    for (int nl = 0; nl < 8; nl++) atomicMax(&bmaxu[nl], __float_as_uint(mxb[nl]));
  }
  __syncthreads();
  if (k < KM) {
#pragma unroll
    for (int nl = 0; nl < 8; nl++) {
      float bmax = fmaxf(__uint_as_float(bmaxu[nl]), 1e-30f);
      float xmax = xmaxs[nl];
      size_t rowA = (size_t)(n0 + nl) * RS;
      unsigned char* rb = Bq + (size_t)(n0 + nl) * RSB;
      A2[rowA + k] = aa[nl];
      rb[k] = (unsigned char)(signed char)lrintf(bb[nl] * (127.f / bmax));
      if (k < 20) {
        A2[rowA + KM + k] = xv[nl][k];
        ((__half*)(rb + 208))[k] = __float2half(xv[nl][k] * (32768.f / xmax));
      }
      if (k == 0) {
        ((float*)(rb + 248))[0] = bmax / 127.f;
        ((float*)(rb + 248))[1] = xmax / 32768.f;
      }
    }
  }
}

// final: agg(20ch bf16) + fin(20->1), no relu, writes d_out.
__global__ void __launch_bounds__(256) aggfin_out_kernel(
    const unsigned short* __restrict__ gd, const int* __restrict__ off,
    const float* __restrict__ xrp,
    const float* __restrict__ W1, const float* __restrict__ b1,
    const float* __restrict__ W2, const float* __restrict__ b2,
    float* __restrict__ out) {
  __shared__ float ag[8][21], xp[8][21], degs[8];
  int tid = threadIdx.x;
  int n0 = blockIdx.x * 8;
  if (tid < 160) {
    int c = tid >> 3, nl = tid & 7;
    int n = n0 + nl;
    int s = off[n], t = off[n + 1];
    const unsigned short* g = gd + (size_t)c * E_EDGES;
    float v = 0.f;
    for (int e = s; e < t; e++) v += bf2f(g[e]);
    ag[nl][c] = v;
    xp[nl][c] = xrp[n * 20 + c];
    if (c == 0) degs[nl] = (float)(t - s);
  }
  __syncthreads();
  if (tid < 8) {
    float v = b1[0] + degs[tid] * b2[0];
#pragma unroll
    for (int c = 0; c < 20; c++) {
      v += ag[tid][c] * W2[c] + xp[tid][c] * W1[c];
    }
    out[n0 + tid] = v;
  }
}

// ---------------- launch ----------------

extern "C" void kernel_launch(void* const* d_in, const int* in_sizes, int n_in,
                              void* d_out, int out_size, void* d_ws, size_t ws_size,
                              hipStream_t stream) {
  const float* features = (const float*)d_in[0];
  const int* edges = (const int*)d_in[1];
  // d_in[2] = weights (unused by reference)

  const float *dW1 = (const float*)d_in[3], *db1 = (const float*)d_in[4],
              *dWm1 = (const float*)d_in[5], *dbm1 = (const float*)d_in[6],
              *dWm2 = (const float*)d_in[7], *dbm2 = (const float*)d_in[8],
              *dW2 = (const float*)d_in[9], *db2 = (const float*)d_in[10];
  const float *hW1 = (const float*)d_in[11], *hb1 = (const float*)d_in[12],
              *hWm1 = (const float*)d_in[13], *hbm1 = (const float*)d_in[14],
              *hWm2 = (const float*)d_in[15], *hbm2 = (const float*)d_in[16],
              *hW2 = (const float*)d_in[17], *hb2 = (const float*)d_in[18];
  const float *oW1 = (const float*)d_in[19], *ob1 = (const float*)d_in[20],
              *oWm1 = (const float*)d_in[21], *obm1 = (const float*)d_in[22],
              *oWm2 = (const float*)d_in[23], *obm2 = (const float*)d_in[24],
              *oW2 = (const float*)d_in[25], *ob2 = (const float*)d_in[26];

  // workspace layout (float units)
  float* fws = (float*)d_ws;
  size_t o = 0;
  float* A2 = fws + o;                           o += (size_t)N_NODES * RS;       // 5.6M
  unsigned char* Bq = (unsigned char*)(fws + o); o += (size_t)N_NODES * RSB / 4;  // 1.6M floats
  unsigned short* gd = (unsigned short*)(fws + o); o += (size_t)20 * E_EDGES / 2; // 4.0M floats (bf16)
  float* xrA = fws + o;                          o += (size_t)N_NODES * 20;
  float* xrB = fws + o;                          o += (size_t)N_NODES * 20;
  int* ip = (int*)(fws + o);
  int* hist = ip;   ip += N_NODES;
  int* off = ip;    ip += N_NODES + 4;
  int* cursor = ip; ip += N_NODES;
  int2* se = (int2*)ip;

  const int B256 = 256;
  const int EDGE_G = E_EDGES / 128;  // 3125, exact (128-thread blocks)
  const int NODE8_G = N_NODES / 8;   // 3125, exact

  // build dst-sorted edge list + CSR offsets (recomputed every launch)
  (void)hipMemsetAsync(hist, 0, N_NODES * sizeof(int), stream);
  hist_kernel<<<(E_EDGES + B256 - 1) / B256, B256, 0, stream>>>(edges, hist);
  scan_kernel<<<1, 1024, 0, stream>>>(hist, off, cursor);

  // layer d: 1 -> 20 (scatter fused into prep)
  scatter_prep_d_kernel<<<NODE8_G, B256, 0, stream>>>(edges, cursor, se, features,
                                                      dWm1, dbm1, A2, Bq, xrA);
  edge_kernel<1><<<EDGE_G, 128, 0, stream>>>(se, A2, Bq, dWm2, dbm2, gd);
  afp1_kernel<<<NODE8_G, B256, 0, stream>>>(gd, off, xrA, dW1, db1, dW2, db2,
                                            hWm1, hbm1, A2, Bq, xrB);

  // hidden1
  edge_kernel<20><<<EDGE_G, 128, 0, stream>>>(se, A2, Bq, hWm2, hbm2, gd);
  afp20_kernel<<<NODE8_G, B256, 0, stream>>>(gd, off, xrB, hW1, hb1, hW2, hb2,
                                             hWm1, hbm1, A2, Bq, xrA);
  // hidden2
  edge_kernel<20><<<EDGE_G, 128, 0, stream>>>(se, A2, Bq, hWm2, hbm2, gd);
  afp20_kernel<<<NODE8_G, B256, 0, stream>>>(gd, off, xrA, hW1, hb1, hW2, hb2,
                                             hWm1, hbm1, A2, Bq, xrB);
  // hidden3 -> preps output layer (oWm1)
  edge_kernel<20><<<EDGE_G, 128, 0, stream>>>(se, A2, Bq, hWm2, hbm2, gd);
  afp20_kernel<<<NODE8_G, B256, 0, stream>>>(gd, off, xrB, hW1, hb1, hW2, hb2,
                                             oWm1, obm1, A2, Bq, xrA);
  // output layer: 20 -> 1 (no trailing relu)
  edge_kernel<20><<<EDGE_G, 128, 0, stream>>>(se, A2, Bq, oWm2, obm2, gd);
  aggfin_out_kernel<<<NODE8_G, B256, 0, stream>>>(gd, off, xrA, oW1, ob1, oW2, ob2,
                                                  (float*)d_out);
}

// Round 18
// 621.875 us; speedup vs baseline: 7.1623x; 1.0622x over previous
//
#include <hip/hip_runtime.h>
#include <hip/hip_fp16.h>

#define N_NODES 25000   // = 3125 * 8 exactly
#define E_EDGES 400000
#define KM 200      // message channels
#define RS 224      // A-row stride (floats): 200 fp32 A | 20 fp32 x | pad (896 B)
#define RSB 256     // B-row stride BYTES: 200 int8 | pad | 20 fp16 x @208 | inv_p,inv_x @248

typedef float v2f __attribute__((ext_vector_type(2)));  // v_pk_fma_f32 operand

__device__ __forceinline__ float2 h2f(unsigned u) {
  return __half22float2(*(const __half2*)&u);
}
__device__ __forceinline__ float4 i8x4f(unsigned u) {
  float4 f;
  f.x = (float)((int)(u << 24) >> 24);
  f.y = (float)((int)(u << 16) >> 24);
  f.z = (float)((int)(u << 8) >> 24);
  f.w = (float)((int)u >> 24);
  return f;
}
// bf16 round-half-up pack / unpack (gd is bf16 to halve its HBM round-trip)
__device__ __forceinline__ unsigned short f2bfr(float v) {
  unsigned u = __float_as_uint(v) + 0x8000u;
  return (unsigned short)(u >> 16);
}
__device__ __forceinline__ float bf2f(unsigned short h) {
  return __uint_as_float((unsigned)h << 16);
}

// Segment sum with batched loads: 8 loads in flight, adds in original order
// (single accumulator, sequential) -> bitwise-identical to the naive loop.
__device__ __forceinline__ float seg_sum_bf16(const unsigned short* __restrict__ g,
                                              int s, int t) {
  float v = 0.f;
  int e = s;
  int t8 = s + ((t - s) & ~7);
  for (; e < t8; e += 8) {
    unsigned short u0 = g[e + 0], u1 = g[e + 1], u2 = g[e + 2], u3 = g[e + 3];
    unsigned short u4 = g[e + 4], u5 = g[e + 5], u6 = g[e + 6], u7 = g[e + 7];
    v += bf2f(u0); v += bf2f(u1); v += bf2f(u2); v += bf2f(u3);
    v += bf2f(u4); v += bf2f(u5); v += bf2f(u6); v += bf2f(u7);
  }
  int t2 = s + ((t - s) & ~1);
  for (; e < t2; e += 2) {
    unsigned short u0 = g[e + 0], u1 = g[e + 1];
    v += bf2f(u0); v += bf2f(u1);
  }
  if (e < t) v += bf2f(g[e]);
  return v;
}

// ---------------- sort-by-dst (CSR build) ----------------

__global__ void hist_kernel(const int* __restrict__ edges, int* __restrict__ hist) {
  int e = blockIdx.x * blockDim.x + threadIdx.x;
  if (e < E_EDGES) atomicAdd(&hist[edges[E_EDGES + e]], 1);
}

__global__ void scan_kernel(const int* __restrict__ hist, int* __restrict__ off,
                            int* __restrict__ cursor) {
  __shared__ int sums[1024];
  const int CH = (N_NODES + 1023) / 1024;  // 25
  int tid = threadIdx.x;
  int base = tid * CH;
  int s = 0;
  for (int i = 0; i < CH; i++) {
    int idx = base + i;
    if (idx < N_NODES) s += hist[idx];
  }
  sums[tid] = s;
  __syncthreads();
  for (int d = 1; d < 1024; d <<= 1) {
    int v = (tid >= d) ? sums[tid - d] : 0;
    __syncthreads();
    sums[tid] += v;
    __syncthreads();
  }
  int run = (tid == 0) ? 0 : sums[tid - 1];
  for (int i = 0; i < CH; i++) {
    int idx = base + i;
    if (idx < N_NODES) {
      off[idx] = run;
      cursor[idx] = run;
      run += hist[idx];
    }
  }
  if (tid == 1023) off[N_NODES] = run;  // == E
}

// ---------------- per-layer kernels ----------------

// Fused: scatter (128 edges/block) + prep layer-d (8 nodes/block).
// prep: A fp32; B int8 (exact bound: max_k |x*wb_k| = |x|*wbmax); x-tail fp16.
__global__ void __launch_bounds__(256) scatter_prep_d_kernel(
    const int* __restrict__ edges, int* __restrict__ cursor, int2* __restrict__ se,
    const float* __restrict__ xin,
    const float* __restrict__ Wm1, const float* __restrict__ bm1,
    float* __restrict__ A2, unsigned char* __restrict__ Bq, float* __restrict__ xr) {
  int tid = threadIdx.x;
  // scatter part: 3125 * 128 = 400000 exactly
  if (tid < 128) {
    int e = blockIdx.x * 128 + tid;
    int s = edges[e];
    int d = edges[E_EDGES + e];
    int pos = atomicAdd(&cursor[d], 1);
    se[pos] = make_int2(s, d);
  }
  // prep part
  __shared__ unsigned wbmaxu;
  if (tid == 0) wbmaxu = 0;
  __syncthreads();
  int k = tid;
  float wa = 0.f, wb = 0.f, bm = 0.f;
  if (k < KM) {
    bm = bm1[k];
    wa = Wm1[k];
    wb = Wm1[KM + k];
  }
  float mb = (k < KM) ? fabsf(wb) : 0.f;
#pragma unroll
  for (int s = 1; s < 64; s <<= 1) mb = fmaxf(mb, __shfl_xor(mb, s));
  if ((k & 63) == 0) atomicMax(&wbmaxu, __float_as_uint(mb));
  __syncthreads();
  float wbmax = fmaxf(__uint_as_float(wbmaxu), 1e-30f);
  int n0 = blockIdx.x * 8;
  for (int i = 0; i < 8; i++) {
    int n = n0 + i;
    float xv = xin[n];
    float bBound = fmaxf(fabsf(xv) * wbmax, 1e-30f);
    float xBound = fmaxf(fabsf(xv), 1e-30f);
    size_t rowA = (size_t)n * RS;
    unsigned char* rb = Bq + (size_t)n * RSB;
    if (k == 0) {
      xr[n] = xv;
      A2[rowA + KM] = xv;
      ((__half*)(rb + 208))[0] = __float2half(xv * (32768.f / xBound));
      ((float*)(rb + 248))[0] = bBound / 127.f;
      ((float*)(rb + 248))[1] = xBound / 32768.f;
    }
    if (k < KM) {
      A2[rowA + k] = bm + xv * wa;
      rb[k] = (unsigned char)(signed char)lrintf(xv * wb * (127.f / bBound));
    }
  }
}

// Edge kernel: one thread per (dst-sorted) edge, 128-thread blocks (grid 3125 exact).
// A fp32 (dst-shared, streamed), B int8 256 B (randomly gathered).
// h_k = relu(A[dst][k] + B8[src][k]*invB); gate = h@Wm2 + bm2 via packed f32
// (v_pk_fma_f32 — gate/Wm2 channel pairs are contiguous); gd [c][e] bf16 nt-stores.
template <int CIN>
__global__ void __launch_bounds__(128) edge_kernel(
    const int2* __restrict__ se,
    const float* __restrict__ A2, const unsigned char* __restrict__ Bq,
    const float* __restrict__ Wm2, const float* __restrict__ bm2,
    unsigned short* __restrict__ gd) {
  int e = blockIdx.x * 128 + threadIdx.x;  // grid exact: no bounds check
  int2 sd = se[e];
  int src = sd.x;
  int dst = sd.y;
  const float* Ar = A2 + (size_t)dst * RS;
  const unsigned char* Br = Bq + (size_t)src * RSB;
  float invB = ((const float*)(Br + 248))[0];
  constexpr int NP = (CIN + 1) / 2;
  v2f gate2[NP];
  if constexpr (CIN == 20) {
#pragma unroll
    for (int i = 0; i < NP; i++) gate2[i] = *(const v2f*)(bm2 + 2 * i);
  } else {
    gate2[0].x = bm2[0];
    gate2[0].y = 0.f;
  }
  // main loop: 12 iters of 16 channels (192), then an 8-channel tail
#pragma unroll 2
  for (int k = 0; k < 192; k += 16) {
    float4 a0 = *(const float4*)(Ar + k);
    float4 a1 = *(const float4*)(Ar + k + 4);
    float4 a2 = *(const float4*)(Ar + k + 8);
    float4 a3 = *(const float4*)(Ar + k + 12);
    uint4 braw = *(const uint4*)(Br + k);  // 16 int8
    float4 f0 = i8x4f(braw.x);
    float4 f1 = i8x4f(braw.y);
    float4 f2 = i8x4f(braw.z);
    float4 f3 = i8x4f(braw.w);
    float h[16];
    h[0] = fmaxf(a0.x + f0.x * invB, 0.f);
    h[1] = fmaxf(a0.y + f0.y * invB, 0.f);
    h[2] = fmaxf(a0.z + f0.z * invB, 0.f);
    h[3] = fmaxf(a0.w + f0.w * invB, 0.f);
    h[4] = fmaxf(a1.x + f1.x * invB, 0.f);
    h[5] = fmaxf(a1.y + f1.y * invB, 0.f);
    h[6] = fmaxf(a1.z + f1.z * invB, 0.f);
    h[7] = fmaxf(a1.w + f1.w * invB, 0.f);
    h[8] = fmaxf(a2.x + f2.x * invB, 0.f);
    h[9] = fmaxf(a2.y + f2.y * invB, 0.f);
    h[10] = fmaxf(a2.z + f2.z * invB, 0.f);
    h[11] = fmaxf(a2.w + f2.w * invB, 0.f);
    h[12] = fmaxf(a3.x + f3.x * invB, 0.f);
    h[13] = fmaxf(a3.y + f3.y * invB, 0.f);
    h[14] = fmaxf(a3.z + f3.z * invB, 0.f);
    h[15] = fmaxf(a3.w + f3.w * invB, 0.f);
    if constexpr (CIN == 20) {
#pragma unroll
      for (int j = 0; j < 16; j++) {
        v2f hj;
        hj.x = h[j];
        hj.y = h[j];
        const v2f* w2 = (const v2f*)(Wm2 + (k + j) * 20);
#pragma unroll
        for (int i = 0; i < 10; i++) gate2[i] += hj * w2[i];
      }
    } else {
      float g = gate2[0].x;
#pragma unroll
      for (int j = 0; j < 16; j++) g += h[j] * Wm2[k + j];
      gate2[0].x = g;
    }
  }
  {  // tail k = 192..199
    float4 a0 = *(const float4*)(Ar + 192);
    float4 a1 = *(const float4*)(Ar + 196);
    uint2 braw = *(const uint2*)(Br + 192);
    float4 f01 = i8x4f(braw.x);
    float4 f23 = i8x4f(braw.y);
    float h[8];
    h[0] = fmaxf(a0.x + f01.x * invB, 0.f);
    h[1] = fmaxf(a0.y + f01.y * invB, 0.f);
    h[2] = fmaxf(a0.z + f01.z * invB, 0.f);
    h[3] = fmaxf(a0.w + f01.w * invB, 0.f);
    h[4] = fmaxf(a1.x + f23.x * invB, 0.f);
    h[5] = fmaxf(a1.y + f23.y * invB, 0.f);
    h[6] = fmaxf(a1.z + f23.z * invB, 0.f);
    h[7] = fmaxf(a1.w + f23.w * invB, 0.f);
    if constexpr (CIN == 20) {
#pragma unroll
      for (int j = 0; j < 8; j++) {
        v2f hj;
        hj.x = h[j];
        hj.y = h[j];
        const v2f* w2 = (const v2f*)(Wm2 + (192 + j) * 20);
#pragma unroll
        for (int i = 0; i < 10; i++) gate2[i] += hj * w2[i];
      }
    } else {
      float g = gate2[0].x;
#pragma unroll
      for (int j = 0; j < 8; j++) g += h[j] * Wm2[192 + j];
      gate2[0].x = g;
    }
  }
  // x-diff tails: A fp32, B fp16-scaled; coalesced nontemporal bf16 stores
  float invXb = ((const float*)(Br + 248))[1];
  const __half* xtb = (const __half*)(Br + 208);
  if constexpr (CIN == 20) {
    unsigned wxb[10];
    {
      uint4 s0 = *(const uint4*)(xtb);
      uint4 s1 = *(const uint4*)(xtb + 8);
      uint2 s2 = *(const uint2*)(xtb + 16);
      wxb[0] = s0.x; wxb[1] = s0.y; wxb[2] = s0.z; wxb[3] = s0.w;
      wxb[4] = s1.x; wxb[5] = s1.y; wxb[6] = s1.z; wxb[7] = s1.w;
      wxb[8] = s2.x; wxb[9] = s2.y;
    }
#pragma unroll
    for (int i = 0; i < 10; i++) {
      float2 xa = *(const float2*)(Ar + KM + 2 * i);
      float2 fb = h2f(wxb[i]);
      int c0 = 2 * i, c1 = 2 * i + 1;
      __builtin_nontemporal_store(f2bfr(gate2[i].x * (xa.x - fb.x * invXb)),
                                  gd + (size_t)c0 * E_EDGES + e);
      __builtin_nontemporal_store(f2bfr(gate2[i].y * (xa.y - fb.y * invXb)),
                                  gd + (size_t)c1 * E_EDGES + e);
    }
  } else {
    float xa = Ar[KM];
    float xb = __half2float(xtb[0]) * invXb;
    __builtin_nontemporal_store(f2bfr(gate2[0].x * (xa - xb)), gd + e);
  }
}

// afp1: after layer-d edge (gd 1-channel bf16). Per block: 8 nodes.
__global__ void __launch_bounds__(256) afp1_kernel(
    const unsigned short* __restrict__ gd, const int* __restrict__ off,
    const float* __restrict__ xrp,
    const float* __restrict__ W1, const float* __restrict__ b1,
    const float* __restrict__ W2, const float* __restrict__ b2,
    const float* __restrict__ Wm1n, const float* __restrict__ bm1n,
    float* __restrict__ A2, unsigned char* __restrict__ Bq, float* __restrict__ xrn) {
  __shared__ float ag[8], xp[8], degs[8];
  __shared__ float xv[8][21];
  __shared__ unsigned bmaxu[8];
  __shared__ float xmaxs[8];
  int tid = threadIdx.x;
  int n0 = blockIdx.x * 8;
  if (tid < 8) {
    bmaxu[tid] = 0;
    int n = n0 + tid;
    int s = off[n], t = off[n + 1];
    ag[tid] = seg_sum_bf16(gd, s, t);
    xp[tid] = xrp[n];
    degs[tid] = (float)(t - s);
  }
  __syncthreads();
  if (tid < 160) {
    int o = tid >> 3, nl = tid & 7;
    float v = b1[o] + degs[nl] * b2[o] + ag[nl] * W2[o] + xp[nl] * W1[o];
    float r = fmaxf(v, 0.f);
    xv[nl][o] = r;
    xrn[(n0 + nl) * 20 + o] = r;
  }
  __syncthreads();
  if (tid < 8) {
    float m = 0.f;
#pragma unroll
    for (int c = 0; c < 20; c++) m = fmaxf(m, xv[tid][c]);
    xmaxs[tid] = fmaxf(m, 1e-30f);
  }
  int k = tid;
  float aa[8], bb[8];
  if (k < KM) {
    float wa[20], wb[20];
    float bm = bm1n[k];
#pragma unroll
    for (int c = 0; c < 20; c++) {
      wa[c] = Wm1n[c * KM + k];
      wb[c] = Wm1n[(20 + c) * KM + k];
    }
#pragma unroll
    for (int nl = 0; nl < 8; nl++) {
      float a = bm, b = 0.f;
#pragma unroll
      for (int c = 0; c < 20; c++) {
        a += xv[nl][c] * wa[c];
        b += xv[nl][c] * wb[c];
      }
      aa[nl] = a;
      bb[nl] = b;
    }
  }
  float mxb[8];
#pragma unroll
  for (int nl = 0; nl < 8; nl++) mxb[nl] = (k < KM) ? fabsf(bb[nl]) : 0.f;
#pragma unroll
  for (int s = 1; s < 64; s <<= 1) {
#pragma unroll
    for (int nl = 0; nl < 8; nl++) mxb[nl] = fmaxf(mxb[nl], __shfl_xor(mxb[nl], s));
  }
  if ((tid & 63) == 0) {
#pragma unroll
    for (int nl = 0; nl < 8; nl++) atomicMax(&bmaxu[nl], __float_as_uint(mxb[nl]));
  }
  __syncthreads();
  if (k < KM) {
#pragma unroll
    for (int nl = 0; nl < 8; nl++) {
      float bmax = fmaxf(__uint_as_float(bmaxu[nl]), 1e-30f);
      float xmax = xmaxs[nl];
      size_t rowA = (size_t)(n0 + nl) * RS;
      unsigned char* rb = Bq + (size_t)(n0 + nl) * RSB;
      A2[rowA + k] = aa[nl];
      rb[k] = (unsigned char)(signed char)lrintf(bb[nl] * (127.f / bmax));
      if (k < 20) {
        A2[rowA + KM + k] = xv[nl][k];
        ((__half*)(rb + 208))[k] = __float2half(xv[nl][k] * (32768.f / xmax));
      }
      if (k == 0) {
        ((float*)(rb + 248))[0] = bmax / 127.f;
        ((float*)(rb + 248))[1] = xmax / 32768.f;
      }
    }
  }
}

// afp20: after a hidden edge (gd 20-channel bf16). Same 3 phases, CIN=20.
__global__ void __launch_bounds__(256) afp20_kernel(
    const unsigned short* __restrict__ gd, const int* __restrict__ off,
    const float* __restrict__ xrp,
    const float* __restrict__ W1, const float* __restrict__ b1,
    const float* __restrict__ W2, const float* __restrict__ b2,
    const float* __restrict__ Wm1n, const float* __restrict__ bm1n,
    float* __restrict__ A2, unsigned char* __restrict__ Bq, float* __restrict__ xrn) {
  __shared__ float ag[8][21], xp[8][21], xv[8][21], degs[8];
  __shared__ unsigned bmaxu[8];
  __shared__ float xmaxs[8];
  int tid = threadIdx.x;
  int n0 = blockIdx.x * 8;
  if (tid < 8) bmaxu[tid] = 0;
  if (tid < 160) {
    int c = tid >> 3, nl = tid & 7;  // adjacent lanes: same c, adjacent n
    int n = n0 + nl;
    int s = off[n], t = off[n + 1];
    ag[nl][c] = seg_sum_bf16(gd + (size_t)c * E_EDGES, s, t);
    xp[nl][c] = xrp[n * 20 + c];
    if (c == 0) degs[nl] = (float)(t - s);
  }
  __syncthreads();
  if (tid < 160) {
    int o = tid >> 3, nl = tid & 7;
    float v = b1[o] + degs[nl] * b2[o];
#pragma unroll
    for (int c = 0; c < 20; c++) {
      v += ag[nl][c] * W2[c * 20 + o] + xp[nl][c] * W1[c * 20 + o];
    }
    float r = fmaxf(v, 0.f);
    xv[nl][o] = r;
    xrn[(n0 + nl) * 20 + o] = r;
  }
  __syncthreads();
  if (tid < 8) {
    float m = 0.f;
#pragma unroll
    for (int c = 0; c < 20; c++) m = fmaxf(m, xv[tid][c]);
    xmaxs[tid] = fmaxf(m, 1e-30f);
  }
  int k = tid;
  float aa[8], bb[8];
  if (k < KM) {
    float wa[20], wb[20];
    float bm = bm1n[k];
#pragma unroll
    for (int c = 0; c < 20; c++) {
      wa[c] = Wm1n[c * KM + k];
      wb[c] = Wm1n[(20 + c) * KM + k];
    }
#pragma unroll
    for (int nl = 0; nl < 8; nl++) {
      float a = bm, b = 0.f;
#pragma unroll
      for (int c = 0; c < 20; c++) {
        a += xv[nl][c] * wa[c];
        b += xv[nl][c] * wb[c];
      }
      aa[nl] = a;
      bb[nl] = b;
    }
  }
  float mxb[8];
#pragma unroll
  for (int nl = 0; nl < 8; nl++) mxb[nl] = (k < KM) ? fabsf(bb[nl]) : 0.f;
#pragma unroll
  for (int s = 1; s < 64; s <<= 1) {
#pragma unroll
    for (int nl = 0; nl < 8; nl++) mxb[nl] = fmaxf(mxb[nl], __shfl_xor(mxb[nl], s));
  }
  if ((tid & 63) == 0) {
#pragma unroll
    for (int nl = 0; nl < 8; nl++) atomicMax(&bmaxu[nl], __float_as_uint(mxb[nl]));
  }
  __syncthreads();
  if (k < KM) {
#pragma unroll
    for (int nl = 0; nl < 8; nl++) {
      float bmax = fmaxf(__uint_as_float(bmaxu[nl]), 1e-30f);
      float xmax = xmaxs[nl];
      size_t rowA = (size_t)(n0 + nl) * RS;
      unsigned char* rb = Bq + (size_t)(n0 + nl) * RSB;
      A2[rowA + k] = aa[nl];
      rb[k] = (unsigned char)(signed char)lrintf(bb[nl] * (127.f / bmax));
      if (k < 20) {
        A2[rowA + KM + k] = xv[nl][k];
        ((__half*)(rb + 208))[k] = __float2half(xv[nl][k] * (32768.f / xmax));
      }
      if (k == 0) {
        ((float*)(rb + 248))[0] = bmax / 127.f;
        ((float*)(rb + 248))[1] = xmax / 32768.f;
      }
    }
  }
}

// final: agg(20ch bf16) + fin(20->1), no relu, writes d_out.
__global__ void __launch_bounds__(256) aggfin_out_kernel(
    const unsigned short* __restrict__ gd, const int* __restrict__ off,
    const float* __restrict__ xrp,
    const float* __restrict__ W1, const float* __restrict__ b1,
    const float* __restrict__ W2, const float* __restrict__ b2,
    float* __restrict__ out) {
  __shared__ float ag[8][21], xp[8][21], degs[8];
  int tid = threadIdx.x;
  int n0 = blockIdx.x * 8;
  if (tid < 160) {
    int c = tid >> 3, nl = tid & 7;
    int n = n0 + nl;
    int s = off[n], t = off[n + 1];
    ag[nl][c] = seg_sum_bf16(gd + (size_t)c * E_EDGES, s, t);
    xp[nl][c] = xrp[n * 20 + c];
    if (c == 0) degs[nl] = (float)(t - s);
  }
  __syncthreads();
  if (tid < 8) {
    float v = b1[0] + degs[tid] * b2[0];
#pragma unroll
    for (int c = 0; c < 20; c++) {
      v += ag[tid][c] * W2[c] + xp[tid][c] * W1[c];
    }
    out[n0 + tid] = v;
  }
}

// ---------------- launch ----------------

extern "C" void kernel_launch(void* const* d_in, const int* in_sizes, int n_in,
                              void* d_out, int out_size, void* d_ws, size_t ws_size,
                              hipStream_t stream) {
  const float* features = (const float*)d_in[0];
  const int* edges = (const int*)d_in[1];
  // d_in[2] = weights (unused by reference)

  const float *dW1 = (const float*)d_in[3], *db1 = (const float*)d_in[4],
              *dWm1 = (const float*)d_in[5], *dbm1 = (const float*)d_in[6],
              *dWm2 = (const float*)d_in[7], *dbm2 = (const float*)d_in[8],
              *dW2 = (const float*)d_in[9], *db2 = (const float*)d_in[10];
  const float *hW1 = (const float*)d_in[11], *hb1 = (const float*)d_in[12],
              *hWm1 = (const float*)d_in[13], *hbm1 = (const float*)d_in[14],
              *hWm2 = (const float*)d_in[15], *hbm2 = (const float*)d_in[16],
              *hW2 = (const float*)d_in[17], *hb2 = (const float*)d_in[18];
  const float *oW1 = (const float*)d_in[19], *ob1 = (const float*)d_in[20],
              *oWm1 = (const float*)d_in[21], *obm1 = (const float*)d_in[22],
              *oWm2 = (const float*)d_in[23], *obm2 = (const float*)d_in[24],
              *oW2 = (const float*)d_in[25], *ob2 = (const float*)d_in[26];

  // workspace layout (float units)
  float* fws = (float*)d_ws;
  size_t o = 0;
  float* A2 = fws + o;                           o += (size_t)N_NODES * RS;       // 5.6M
  unsigned char* Bq = (unsigned char*)(fws + o); o += (size_t)N_NODES * RSB / 4;  // 1.6M floats
  unsigned short* gd = (unsigned short*)(fws + o); o += (size_t)20 * E_EDGES / 2; // 4.0M floats (bf16)
  float* xrA = fws + o;                          o += (size_t)N_NODES * 20;
  float* xrB = fws + o;                          o += (size_t)N_NODES * 20;
  int* ip = (int*)(fws + o);
  int* hist = ip;   ip += N_NODES;
  int* off = ip;    ip += N_NODES + 4;
  int* cursor = ip; ip += N_NODES;
  int2* se = (int2*)ip;

  const int B256 = 256;
  const int EDGE_G = E_EDGES / 128;  // 3125, exact (128-thread blocks)
  const int NODE8_G = N_NODES / 8;   // 3125, exact

  // build dst-sorted edge list + CSR offsets (recomputed every launch)
  (void)hipMemsetAsync(hist, 0, N_NODES * sizeof(int), stream);
  hist_kernel<<<(E_EDGES + B256 - 1) / B256, B256, 0, stream>>>(edges, hist);
  scan_kernel<<<1, 1024, 0, stream>>>(hist, off, cursor);

  // layer d: 1 -> 20 (scatter fused into prep)
  scatter_prep_d_kernel<<<NODE8_G, B256, 0, stream>>>(edges, cursor, se, features,
                                                      dWm1, dbm1, A2, Bq, xrA);
  edge_kernel<1><<<EDGE_G, 128, 0, stream>>>(se, A2, Bq, dWm2, dbm2, gd);
  afp1_kernel<<<NODE8_G, B256, 0, stream>>>(gd, off, xrA, dW1, db1, dW2, db2,
                                            hWm1, hbm1, A2, Bq, xrB);

  // hidden1
  edge_kernel<20><<<EDGE_G, 128, 0, stream>>>(se, A2, Bq, hWm2, hbm2, gd);
  afp20_kernel<<<NODE8_G, B256, 0, stream>>>(gd, off, xrB, hW1, hb1, hW2, hb2,
                                             hWm1, hbm1, A2, Bq, xrA);
  // hidden2
  edge_kernel<20><<<EDGE_G, 128, 0, stream>>>(se, A2, Bq, hWm2, hbm2, gd);
  afp20_kernel<<<NODE8_G, B256, 0, stream>>>(gd, off, xrA, hW1, hb1, hW2, hb2,
                                             hWm1, hbm1, A2, Bq, xrB);
  // hidden3 -> preps output layer (oWm1)
  edge_kernel<20><<<EDGE_G, 128, 0, stream>>>(se, A2, Bq, hWm2, hbm2, gd);
  afp20_kernel<<<NODE8_G, B256, 0, stream>>>(gd, off, xrB, hW1, hb1, hW2, hb2,
                                             oWm1, obm1, A2, Bq, xrA);
  // output layer: 20 -> 1 (no trailing relu)
  edge_kernel<20><<<EDGE_G, 128, 0, stream>>>(se, A2, Bq, oWm2, obm2, gd);
  aggfin_out_kernel<<<NODE8_G, B256, 0, stream>>>(gd, off, xrA, oW1, ob1, oW2, ob2,
                                                  (float*)d_out);
}

// Round 19
// 584.079 us; speedup vs baseline: 7.6257x; 1.0647x over previous
//
#include <hip/hip_runtime.h>
#include <hip/hip_fp16.h>

#define N_NODES 25000   // = 3125 * 8 exactly
#define E_EDGES 400000
#define KM 200      // message channels
#define RS 224      // A-row stride (floats): 200 fp32 A | 20 fp32 x | pad (896 B)
#define RSB 256     // B-row stride BYTES: 200 int8 | pad | 20 fp16 x @208 | inv_p,inv_x @248

typedef float v2f __attribute__((ext_vector_type(2)));  // v_pk_fma_f32 operand

__device__ __forceinline__ float2 h2f(unsigned u) {
  return __half22float2(*(const __half2*)&u);
}
__device__ __forceinline__ float4 i8x4f(unsigned u) {
  float4 f;
  f.x = (float)((int)(u << 24) >> 24);
  f.y = (float)((int)(u << 16) >> 24);
  f.z = (float)((int)(u << 8) >> 24);
  f.w = (float)((int)u >> 24);
  return f;
}
// bf16 round-half-up pack / unpack (gd is bf16 to halve its HBM round-trip)
__device__ __forceinline__ unsigned short f2bfr(float v) {
  unsigned u = __float_as_uint(v) + 0x8000u;
  return (unsigned short)(u >> 16);
}
__device__ __forceinline__ float bf2f(unsigned short h) {
  return __uint_as_float((unsigned)h << 16);
}

// Segment sum with batched loads: 8 loads in flight, adds in original order
// (single accumulator, sequential) -> bitwise-identical to the naive loop.
__device__ __forceinline__ float seg_sum_bf16(const unsigned short* __restrict__ g,
                                              int s, int t) {
  float v = 0.f;
  int e = s;
  int t8 = s + ((t - s) & ~7);
  for (; e < t8; e += 8) {
    unsigned short u0 = g[e + 0], u1 = g[e + 1], u2 = g[e + 2], u3 = g[e + 3];
    unsigned short u4 = g[e + 4], u5 = g[e + 5], u6 = g[e + 6], u7 = g[e + 7];
    v += bf2f(u0); v += bf2f(u1); v += bf2f(u2); v += bf2f(u3);
    v += bf2f(u4); v += bf2f(u5); v += bf2f(u6); v += bf2f(u7);
  }
  int t2 = s + ((t - s) & ~1);
  for (; e < t2; e += 2) {
    unsigned short u0 = g[e + 0], u1 = g[e + 1];
    v += bf2f(u0); v += bf2f(u1);
  }
  if (e < t) v += bf2f(g[e]);
  return v;
}

// ---------------- sort-by-dst (CSR build) ----------------

__global__ void hist_kernel(const int* __restrict__ edges, int* __restrict__ hist) {
  int e = blockIdx.x * blockDim.x + threadIdx.x;
  if (e < E_EDGES) atomicAdd(&hist[edges[E_EDGES + e]], 1);
}

__global__ void scan_kernel(const int* __restrict__ hist, int* __restrict__ off,
                            int* __restrict__ cursor) {
  __shared__ int sums[1024];
  const int CH = (N_NODES + 1023) / 1024;  // 25
  int tid = threadIdx.x;
  int base = tid * CH;
  int s = 0;
  for (int i = 0; i < CH; i++) {
    int idx = base + i;
    if (idx < N_NODES) s += hist[idx];
  }
  sums[tid] = s;
  __syncthreads();
  for (int d = 1; d < 1024; d <<= 1) {
    int v = (tid >= d) ? sums[tid - d] : 0;
    __syncthreads();
    sums[tid] += v;
    __syncthreads();
  }
  int run = (tid == 0) ? 0 : sums[tid - 1];
  for (int i = 0; i < CH; i++) {
    int idx = base + i;
    if (idx < N_NODES) {
      off[idx] = run;
      cursor[idx] = run;
      run += hist[idx];
    }
  }
  if (tid == 1023) off[N_NODES] = run;  // == E
}

// ---------------- per-layer kernels ----------------

// Fused: scatter (128 edges/block) + prep layer-d (8 nodes/block).
// prep: A fp32; B int8 (exact bound: max_k |x*wb_k| = |x|*wbmax); x-tail fp16.
__global__ void __launch_bounds__(256) scatter_prep_d_kernel(
    const int* __restrict__ edges, int* __restrict__ cursor, int2* __restrict__ se,
    const float* __restrict__ xin,
    const float* __restrict__ Wm1, const float* __restrict__ bm1,
    float* __restrict__ A2, unsigned char* __restrict__ Bq, float* __restrict__ xr) {
  int tid = threadIdx.x;
  // scatter part: 3125 * 128 = 400000 exactly
  if (tid < 128) {
    int e = blockIdx.x * 128 + tid;
    int s = edges[e];
    int d = edges[E_EDGES + e];
    int pos = atomicAdd(&cursor[d], 1);
    se[pos] = make_int2(s, d);
  }
  // prep part
  __shared__ unsigned wbmaxu;
  if (tid == 0) wbmaxu = 0;
  __syncthreads();
  int k = tid;
  float wa = 0.f, wb = 0.f, bm = 0.f;
  if (k < KM) {
    bm = bm1[k];
    wa = Wm1[k];
    wb = Wm1[KM + k];
  }
  float mb = (k < KM) ? fabsf(wb) : 0.f;
#pragma unroll
  for (int s = 1; s < 64; s <<= 1) mb = fmaxf(mb, __shfl_xor(mb, s));
  if ((k & 63) == 0) atomicMax(&wbmaxu, __float_as_uint(mb));
  __syncthreads();
  float wbmax = fmaxf(__uint_as_float(wbmaxu), 1e-30f);
  int n0 = blockIdx.x * 8;
  for (int i = 0; i < 8; i++) {
    int n = n0 + i;
    float xv = xin[n];
    float bBound = fmaxf(fabsf(xv) * wbmax, 1e-30f);
    float xBound = fmaxf(fabsf(xv), 1e-30f);
    size_t rowA = (size_t)n * RS;
    unsigned char* rb = Bq + (size_t)n * RSB;
    if (k == 0) {
      xr[n] = xv;
      A2[rowA + KM] = xv;
      ((__half*)(rb + 208))[0] = __float2half(xv * (32768.f / xBound));
      ((float*)(rb + 248))[0] = bBound / 127.f;
      ((float*)(rb + 248))[1] = xBound / 32768.f;
    }
    if (k < KM) {
      A2[rowA + k] = bm + xv * wa;
      rb[k] = (unsigned char)(signed char)lrintf(xv * wb * (127.f / bBound));
    }
  }
}

// Edge kernel: one thread per (dst-sorted) edge, 128-thread blocks (grid 3125 exact).
// A fp32 (dst-shared, streamed), B int8 256 B gathered as ONE full-row prefetch
// (16 uint4 upfront -> all 4 cache lines of the row in flight concurrently,
// one miss round-trip instead of 2-3 serialized ones).
// h_k = relu(A[dst][k] + B8[src][k]*invB); gate = h@Wm2 + bm2 via v_pk_fma_f32;
// gd [c][e] bf16 nt-stores.
template <int CIN>
__global__ void __launch_bounds__(128) edge_kernel(
    const int2* __restrict__ se,
    const float* __restrict__ A2, const unsigned char* __restrict__ Bq,
    const float* __restrict__ Wm2, const float* __restrict__ bm2,
    unsigned short* __restrict__ gd) {
  int e = blockIdx.x * 128 + threadIdx.x;  // grid exact: no bounds check
  int2 sd = se[e];
  int src = sd.x;
  int dst = sd.y;
  const float* Ar = A2 + (size_t)dst * RS;
  const uint4* Br4 = (const uint4*)(Bq + (size_t)src * RSB);
  uint4 r[16];
#pragma unroll
  for (int i = 0; i < 16; i++) r[i] = Br4[i];
  float invB = __uint_as_float(r[15].z);
  float invXb = __uint_as_float(r[15].w);
  constexpr int NP = (CIN + 1) / 2;
  v2f gate2[NP];
  if constexpr (CIN == 20) {
#pragma unroll
    for (int i = 0; i < NP; i++) gate2[i] = *(const v2f*)(bm2 + 2 * i);
  } else {
    gate2[0].x = bm2[0];
    gate2[0].y = 0.f;
  }
  // main loop: 12 iters of 16 channels (192), then an 8-channel tail
#pragma unroll
  for (int kk = 0; kk < 12; kk++) {
    const int k = kk * 16;
    float4 a0 = *(const float4*)(Ar + k);
    float4 a1 = *(const float4*)(Ar + k + 4);
    float4 a2 = *(const float4*)(Ar + k + 8);
    float4 a3 = *(const float4*)(Ar + k + 12);
    float4 f0 = i8x4f(r[kk].x);
    float4 f1 = i8x4f(r[kk].y);
    float4 f2 = i8x4f(r[kk].z);
    float4 f3 = i8x4f(r[kk].w);
    float h[16];
    h[0] = fmaxf(a0.x + f0.x * invB, 0.f);
    h[1] = fmaxf(a0.y + f0.y * invB, 0.f);
    h[2] = fmaxf(a0.z + f0.z * invB, 0.f);
    h[3] = fmaxf(a0.w + f0.w * invB, 0.f);
    h[4] = fmaxf(a1.x + f1.x * invB, 0.f);
    h[5] = fmaxf(a1.y + f1.y * invB, 0.f);
    h[6] = fmaxf(a1.z + f1.z * invB, 0.f);
    h[7] = fmaxf(a1.w + f1.w * invB, 0.f);
    h[8] = fmaxf(a2.x + f2.x * invB, 0.f);
    h[9] = fmaxf(a2.y + f2.y * invB, 0.f);
    h[10] = fmaxf(a2.z + f2.z * invB, 0.f);
    h[11] = fmaxf(a2.w + f2.w * invB, 0.f);
    h[12] = fmaxf(a3.x + f3.x * invB, 0.f);
    h[13] = fmaxf(a3.y + f3.y * invB, 0.f);
    h[14] = fmaxf(a3.z + f3.z * invB, 0.f);
    h[15] = fmaxf(a3.w + f3.w * invB, 0.f);
    if constexpr (CIN == 20) {
#pragma unroll
      for (int j = 0; j < 16; j++) {
        v2f hj;
        hj.x = h[j];
        hj.y = h[j];
        const v2f* w2 = (const v2f*)(Wm2 + (k + j) * 20);
#pragma unroll
        for (int i = 0; i < 10; i++) gate2[i] += hj * w2[i];
      }
    } else {
      float g = gate2[0].x;
#pragma unroll
      for (int j = 0; j < 16; j++) g += h[j] * Wm2[k + j];
      gate2[0].x = g;
    }
  }
  {  // tail k = 192..199 (r[12].x, r[12].y)
    float4 a0 = *(const float4*)(Ar + 192);
    float4 a1 = *(const float4*)(Ar + 196);
    float4 f01 = i8x4f(r[12].x);
    float4 f23 = i8x4f(r[12].y);
    float h[8];
    h[0] = fmaxf(a0.x + f01.x * invB, 0.f);
    h[1] = fmaxf(a0.y + f01.y * invB, 0.f);
    h[2] = fmaxf(a0.z + f01.z * invB, 0.f);
    h[3] = fmaxf(a0.w + f01.w * invB, 0.f);
    h[4] = fmaxf(a1.x + f23.x * invB, 0.f);
    h[5] = fmaxf(a1.y + f23.y * invB, 0.f);
    h[6] = fmaxf(a1.z + f23.z * invB, 0.f);
    h[7] = fmaxf(a1.w + f23.w * invB, 0.f);
    if constexpr (CIN == 20) {
#pragma unroll
      for (int j = 0; j < 8; j++) {
        v2f hj;
        hj.x = h[j];
        hj.y = h[j];
        const v2f* w2 = (const v2f*)(Wm2 + (192 + j) * 20);
#pragma unroll
        for (int i = 0; i < 10; i++) gate2[i] += hj * w2[i];
      }
    } else {
      float g = gate2[0].x;
#pragma unroll
      for (int j = 0; j < 8; j++) g += h[j] * Wm2[192 + j];
      gate2[0].x = g;
    }
  }
  // x-diff tails: A fp32, B fp16-scaled (bytes 208..247 = r[13], r[14], r[15].xy)
  if constexpr (CIN == 20) {
    unsigned wxb[10] = {r[13].x, r[13].y, r[13].z, r[13].w,
                        r[14].x, r[14].y, r[14].z, r[14].w,
                        r[15].x, r[15].y};
#pragma unroll
    for (int i = 0; i < 10; i++) {
      float2 xa = *(const float2*)(Ar + KM + 2 * i);
      float2 fb = h2f(wxb[i]);
      int c0 = 2 * i, c1 = 2 * i + 1;
      __builtin_nontemporal_store(f2bfr(gate2[i].x * (xa.x - fb.x * invXb)),
                                  gd + (size_t)c0 * E_EDGES + e);
      __builtin_nontemporal_store(f2bfr(gate2[i].y * (xa.y - fb.y * invXb)),
                                  gd + (size_t)c1 * E_EDGES + e);
    }
  } else {
    float xa = Ar[KM];
    float xb = h2f(r[13].x).x * invXb;
    __builtin_nontemporal_store(f2bfr(gate2[0].x * (xa - xb)), gd + e);
  }
}

// afp1: after layer-d edge (gd 1-channel bf16). Per block: 8 nodes.
__global__ void __launch_bounds__(256) afp1_kernel(
    const unsigned short* __restrict__ gd, const int* __restrict__ off,
    const float* __restrict__ xrp,
    const float* __restrict__ W1, const float* __restrict__ b1,
    const float* __restrict__ W2, const float* __restrict__ b2,
    const float* __restrict__ Wm1n, const float* __restrict__ bm1n,
    float* __restrict__ A2, unsigned char* __restrict__ Bq, float* __restrict__ xrn) {
  __shared__ float ag[8], xp[8], degs[8];
  __shared__ float xv[8][21];
  __shared__ unsigned bmaxu[8];
  __shared__ float xmaxs[8];
  int tid = threadIdx.x;
  int n0 = blockIdx.x * 8;
  if (tid < 8) {
    bmaxu[tid] = 0;
    int n = n0 + tid;
    int s = off[n], t = off[n + 1];
    ag[tid] = seg_sum_bf16(gd, s, t);
    xp[tid] = xrp[n];
    degs[tid] = (float)(t - s);
  }
  __syncthreads();
  if (tid < 160) {
    int o = tid >> 3, nl = tid & 7;
    float v = b1[o] + degs[nl] * b2[o] + ag[nl] * W2[o] + xp[nl] * W1[o];
    float r = fmaxf(v, 0.f);
    xv[nl][o] = r;
    xrn[(n0 + nl) * 20 + o] = r;
  }
  __syncthreads();
  if (tid < 8) {
    float m = 0.f;
#pragma unroll
    for (int c = 0; c < 20; c++) m = fmaxf(m, xv[tid][c]);
    xmaxs[tid] = fmaxf(m, 1e-30f);
  }
  int k = tid;
  float aa[8], bb[8];
  if (k < KM) {
    v2f wab[20];  // {wa[c], wb[c]} -> (a,b) accumulate via one pk_fma
    float bm = bm1n[k];
#pragma unroll
    for (int c = 0; c < 20; c++) {
      wab[c].x = Wm1n[c * KM + k];
      wab[c].y = Wm1n[(20 + c) * KM + k];
    }
#pragma unroll
    for (int nl = 0; nl < 8; nl++) {
      v2f acc;
      acc.x = bm;
      acc.y = 0.f;
#pragma unroll
      for (int c = 0; c < 20; c++) {
        v2f xc;
        xc.x = xv[nl][c];
        xc.y = xv[nl][c];
        acc += xc * wab[c];
      }
      aa[nl] = acc.x;
      bb[nl] = acc.y;
    }
  }
  float mxb[8];
#pragma unroll
  for (int nl = 0; nl < 8; nl++) mxb[nl] = (k < KM) ? fabsf(bb[nl]) : 0.f;
#pragma unroll
  for (int s = 1; s < 64; s <<= 1) {
#pragma unroll
    for (int nl = 0; nl < 8; nl++) mxb[nl] = fmaxf(mxb[nl], __shfl_xor(mxb[nl], s));
  }
  if ((tid & 63) == 0) {
#pragma unroll
    for (int nl = 0; nl < 8; nl++) atomicMax(&bmaxu[nl], __float_as_uint(mxb[nl]));
  }
  __syncthreads();
  if (k < KM) {
#pragma unroll
    for (int nl = 0; nl < 8; nl++) {
      float bmax = fmaxf(__uint_as_float(bmaxu[nl]), 1e-30f);
      float xmax = xmaxs[nl];
      size_t rowA = (size_t)(n0 + nl) * RS;
      unsigned char* rb = Bq + (size_t)(n0 + nl) * RSB;
      A2[rowA + k] = aa[nl];
      rb[k] = (unsigned char)(signed char)lrintf(bb[nl] * (127.f / bmax));
      if (k < 20) {
        A2[rowA + KM + k] = xv[nl][k];
        ((__half*)(rb + 208))[k] = __float2half(xv[nl][k] * (32768.f / xmax));
      }
      if (k == 0) {
        ((float*)(rb + 248))[0] = bmax / 127.f;
        ((float*)(rb + 248))[1] = xmax / 32768.f;
      }
    }
  }
}

// afp20: after a hidden edge (gd 20-channel bf16). Same 3 phases, CIN=20.
__global__ void __launch_bounds__(256) afp20_kernel(
    const unsigned short* __restrict__ gd, const int* __restrict__ off,
    const float* __restrict__ xrp,
    const float* __restrict__ W1, const float* __restrict__ b1,
    const float* __restrict__ W2, const float* __restrict__ b2,
    const float* __restrict__ Wm1n, const float* __restrict__ bm1n,
    float* __restrict__ A2, unsigned char* __restrict__ Bq, float* __restrict__ xrn) {
  __shared__ float ag[8][21], xp[8][21], xv[8][21], degs[8];
  __shared__ unsigned bmaxu[8];
  __shared__ float xmaxs[8];
  int tid = threadIdx.x;
  int n0 = blockIdx.x * 8;
  if (tid < 8) bmaxu[tid] = 0;
  if (tid < 160) {
    int c = tid >> 3, nl = tid & 7;  // adjacent lanes: same c, adjacent n
    int n = n0 + nl;
    int s = off[n], t = off[n + 1];
    ag[nl][c] = seg_sum_bf16(gd + (size_t)c * E_EDGES, s, t);
    xp[nl][c] = xrp[n * 20 + c];
    if (c == 0) degs[nl] = (float)(t - s);
  }
  __syncthreads();
  if (tid < 160) {
    int o = tid >> 3, nl = tid & 7;
    float v = b1[o] + degs[nl] * b2[o];
#pragma unroll
    for (int c = 0; c < 20; c++) {
      v += ag[nl][c] * W2[c * 20 + o] + xp[nl][c] * W1[c * 20 + o];
    }
    float r = fmaxf(v, 0.f);
    xv[nl][o] = r;
    xrn[(n0 + nl) * 20 + o] = r;
  }
  __syncthreads();
  if (tid < 8) {
    float m = 0.f;
#pragma unroll
    for (int c = 0; c < 20; c++) m = fmaxf(m, xv[tid][c]);
    xmaxs[tid] = fmaxf(m, 1e-30f);
  }
  int k = tid;
  float aa[8], bb[8];
  if (k < KM) {
    v2f wab[20];  // {wa[c], wb[c]} -> (a,b) accumulate via one pk_fma
    float bm = bm1n[k];
#pragma unroll
    for (int c = 0; c < 20; c++) {
      wab[c].x = Wm1n[c * KM + k];
      wab[c].y = Wm1n[(20 + c) * KM + k];
    }
#pragma unroll
    for (int nl = 0; nl < 8; nl++) {
      v2f acc;
      acc.x = bm;
      acc.y = 0.f;
#pragma unroll
      for (int c = 0; c < 20; c++) {
        v2f xc;
        xc.x = xv[nl][c];
        xc.y = xv[nl][c];
        acc += xc * wab[c];
      }
      aa[nl] = acc.x;
      bb[nl] = acc.y;
    }
  }
  float mxb[8];
#pragma unroll
  for (int nl = 0; nl < 8; nl++) mxb[nl] = (k < KM) ? fabsf(bb[nl]) : 0.f;
#pragma unroll
  for (int s = 1; s < 64; s <<= 1) {
#pragma unroll
    for (int nl = 0; nl < 8; nl++) mxb[nl] = fmaxf(mxb[nl], __shfl_xor(mxb[nl], s));
  }
  if ((tid & 63) == 0) {
#pragma unroll
    for (int nl = 0; nl < 8; nl++) atomicMax(&bmaxu[nl], __float_as_uint(mxb[nl]));
  }
  __syncthreads();
  if (k < KM) {
#pragma unroll
    for (int nl = 0; nl < 8; nl++) {
      float bmax = fmaxf(__uint_as_float(bmaxu[nl]), 1e-30f);
      float xmax = xmaxs[nl];
      size_t rowA = (size_t)(n0 + nl) * RS;
      unsigned char* rb = Bq + (size_t)(n0 + nl) * RSB;
      A2[rowA + k] = aa[nl];
      rb[k] = (unsigned char)(signed char)lrintf(bb[nl] * (127.f / bmax));
      if (k < 20) {
        A2[rowA + KM + k] = xv[nl][k];
        ((__half*)(rb + 208))[k] = __float2half(xv[nl][k] * (32768.f / xmax));
      }
      if (k == 0) {
        ((float*)(rb + 248))[0] = bmax / 127.f;
        ((float*)(rb + 248))[1] = xmax / 32768.f;
      }
    }
  }
}

// final: agg(20ch bf16) + fin(20->1), no relu, writes d_out.
__global__ void __launch_bounds__(256) aggfin_out_kernel(
    const unsigned short* __restrict__ gd, const int* __restrict__ off,
    const float* __restrict__ xrp,
    const float* __restrict__ W1, const float* __restrict__ b1,
    const float* __restrict__ W2, const float* __restrict__ b2,
    float* __restrict__ out) {
  __shared__ float ag[8][21], xp[8][21], degs[8];
  int tid = threadIdx.x;
  int n0 = blockIdx.x * 8;
  if (tid < 160) {
    int c = tid >> 3, nl = tid & 7;
    int n = n0 + nl;
    int s = off[n], t = off[n + 1];
    ag[nl][c] = seg_sum_bf16(gd + (size_t)c * E_EDGES, s, t);
    xp[nl][c] = xrp[n * 20 + c];
    if (c == 0) degs[nl] = (float)(t - s);
  }
  __syncthreads();
  if (tid < 8) {
    float v = b1[0] + degs[tid] * b2[0];
#pragma unroll
    for (int c = 0; c < 20; c++) {
      v += ag[tid][c] * W2[c] + xp[tid][c] * W1[c];
    }
    out[n0 + tid] = v;
  }
}

// ---------------- launch ----------------

extern "C" void kernel_launch(void* const* d_in, const int* in_sizes, int n_in,
                              void* d_out, int out_size, void* d_ws, size_t ws_size,
                              hipStream_t stream) {
  const float* features = (const float*)d_in[0];
  const int* edges = (const int*)d_in[1];
  // d_in[2] = weights (unused by reference)

  const float *dW1 = (const float*)d_in[3], *db1 = (const float*)d_in[4],
              *dWm1 = (const float*)d_in[5], *dbm1 = (const float*)d_in[6],
              *dWm2 = (const float*)d_in[7], *dbm2 = (const float*)d_in[8],
              *dW2 = (const float*)d_in[9], *db2 = (const float*)d_in[10];
  const float *hW1 = (const float*)d_in[11], *hb1 = (const float*)d_in[12],
              *hWm1 = (const float*)d_in[13], *hbm1 = (const float*)d_in[14],
              *hWm2 = (const float*)d_in[15], *hbm2 = (const float*)d_in[16],
              *hW2 = (const float*)d_in[17], *hb2 = (const float*)d_in[18];
  const float *oW1 = (const float*)d_in[19], *ob1 = (const float*)d_in[20],
              *oWm1 = (const float*)d_in[21], *obm1 = (const float*)d_in[22],
              *oWm2 = (const float*)d_in[23], *obm2 = (const float*)d_in[24],
              *oW2 = (const float*)d_in[25], *ob2 = (const float*)d_in[26];

  // workspace layout (float units)
  float* fws = (float*)d_ws;
  size_t o = 0;
  float* A2 = fws + o;                           o += (size_t)N_NODES * RS;       // 5.6M
  unsigned char* Bq = (unsigned char*)(fws + o); o += (size_t)N_NODES * RSB / 4;  // 1.6M floats
  unsigned short* gd = (unsigned short*)(fws + o); o += (size_t)20 * E_EDGES / 2; // 4.0M floats (bf16)
  float* xrA = fws + o;                          o += (size_t)N_NODES * 20;
  float* xrB = fws + o;                          o += (size_t)N_NODES * 20;
  int* ip = (int*)(fws + o);
  int* hist = ip;   ip += N_NODES;
  int* off = ip;    ip += N_NODES + 4;
  int* cursor = ip; ip += N_NODES;
  int2* se = (int2*)ip;

  const int B256 = 256;
  const int EDGE_G = E_EDGES / 128;  // 3125, exact (128-thread blocks)
  const int NODE8_G = N_NODES / 8;   // 3125, exact

  // build dst-sorted edge list + CSR offsets (recomputed every launch)
  (void)hipMemsetAsync(hist, 0, N_NODES * sizeof(int), stream);
  hist_kernel<<<(E_EDGES + B256 - 1) / B256, B256, 0, stream>>>(edges, hist);
  scan_kernel<<<1, 1024, 0, stream>>>(hist, off, cursor);

  // layer d: 1 -> 20 (scatter fused into prep)
  scatter_prep_d_kernel<<<NODE8_G, B256, 0, stream>>>(edges, cursor, se, features,
                                                      dWm1, dbm1, A2, Bq, xrA);
  edge_kernel<1><<<EDGE_G, 128, 0, stream>>>(se, A2, Bq, dWm2, dbm2, gd);
  afp1_kernel<<<NODE8_G, B256, 0, stream>>>(gd, off, xrA, dW1, db1, dW2, db2,
                                            hWm1, hbm1, A2, Bq, xrB);

  // hidden1
  edge_kernel<20><<<EDGE_G, 128, 0, stream>>>(se, A2, Bq, hWm2, hbm2, gd);
  afp20_kernel<<<NODE8_G, B256, 0, stream>>>(gd, off, xrB, hW1, hb1, hW2, hb2,
                                             hWm1, hbm1, A2, Bq, xrA);
  // hidden2
  edge_kernel<20><<<EDGE_G, 128, 0, stream>>>(se, A2, Bq, hWm2, hbm2, gd);
  afp20_kernel<<<NODE8_G, B256, 0, stream>>>(gd, off, xrA, hW1, hb1, hW2, hb2,
                                             hWm1, hbm1, A2, Bq, xrB);
  // hidden3 -> preps output layer (oWm1)
  edge_kernel<20><<<EDGE_G, 128, 0, stream>>>(se, A2, Bq, hWm2, hbm2, gd);
  afp20_kernel<<<NODE8_G, B256, 0, stream>>>(gd, off, xrB, hW1, hb1, hW2, hb2,
                                             oWm1, obm1, A2, Bq, xrA);
  // output layer: 20 -> 1 (no trailing relu)
  edge_kernel<20><<<EDGE_G, 128, 0, stream>>>(se, A2, Bq, oWm2, obm2, gd);
  aggfin_out_kernel<<<NODE8_G, B256, 0, stream>>>(gd, off, xrA, oW1, ob1, oW2, ob2,
                                                  (float*)d_out);
}

// Round 20
// 561.858 us; speedup vs baseline: 7.9273x; 1.0395x over previous
//
#include <hip/hip_runtime.h>
#include <hip/hip_fp16.h>

#define N_NODES 25000   // = 3125 * 8 exactly
#define E_EDGES 400000
#define KM 200      // message channels
#define RS 224      // A-row stride (floats): 200 fp32 A | 20 fp32 x | pad (896 B)
#define RSB 256     // B-row stride BYTES: 200 int8 | pad | 20 fp16 x @208 | inv_p,inv_x @248

typedef float v2f __attribute__((ext_vector_type(2)));  // v_pk_fma_f32 operand

__device__ __forceinline__ float2 h2f(unsigned u) {
  return __half22float2(*(const __half2*)&u);
}
__device__ __forceinline__ float4 i8x4f(unsigned u) {
  float4 f;
  f.x = (float)((int)(u << 24) >> 24);
  f.y = (float)((int)(u << 16) >> 24);
  f.z = (float)((int)(u << 8) >> 24);
  f.w = (float)((int)u >> 24);
  return f;
}
// bf16 round-half-up pack / unpack (gd is bf16 to halve its HBM round-trip)
__device__ __forceinline__ unsigned short f2bfr(float v) {
  unsigned u = __float_as_uint(v) + 0x8000u;
  return (unsigned short)(u >> 16);
}
__device__ __forceinline__ float bf2f(unsigned short h) {
  return __uint_as_float((unsigned)h << 16);
}

// Segment sum with batched loads: 8 loads in flight, adds in original order
// (single accumulator, sequential) -> bitwise-identical to the naive loop.
__device__ __forceinline__ float seg_sum_bf16(const unsigned short* __restrict__ g,
                                              int s, int t) {
  float v = 0.f;
  int e = s;
  int t8 = s + ((t - s) & ~7);
  for (; e < t8; e += 8) {
    unsigned short u0 = g[e + 0], u1 = g[e + 1], u2 = g[e + 2], u3 = g[e + 3];
    unsigned short u4 = g[e + 4], u5 = g[e + 5], u6 = g[e + 6], u7 = g[e + 7];
    v += bf2f(u0); v += bf2f(u1); v += bf2f(u2); v += bf2f(u3);
    v += bf2f(u4); v += bf2f(u5); v += bf2f(u6); v += bf2f(u7);
  }
  int t2 = s + ((t - s) & ~1);
  for (; e < t2; e += 2) {
    unsigned short u0 = g[e + 0], u1 = g[e + 1];
    v += bf2f(u0); v += bf2f(u1);
  }
  if (e < t) v += bf2f(g[e]);
  return v;
}

// ---------------- sort-by-dst (CSR build) ----------------

__global__ void hist_kernel(const int* __restrict__ edges, int* __restrict__ hist) {
  int e = blockIdx.x * blockDim.x + threadIdx.x;
  if (e < E_EDGES) atomicAdd(&hist[edges[E_EDGES + e]], 1);
}

__global__ void scan_kernel(const int* __restrict__ hist, int* __restrict__ off,
                            int* __restrict__ cursor) {
  __shared__ int sums[1024];
  const int CH = (N_NODES + 1023) / 1024;  // 25
  int tid = threadIdx.x;
  int base = tid * CH;
  int s = 0;
  for (int i = 0; i < CH; i++) {
    int idx = base + i;
    if (idx < N_NODES) s += hist[idx];
  }
  sums[tid] = s;
  __syncthreads();
  for (int d = 1; d < 1024; d <<= 1) {
    int v = (tid >= d) ? sums[tid - d] : 0;
    __syncthreads();
    sums[tid] += v;
    __syncthreads();
  }
  int run = (tid == 0) ? 0 : sums[tid - 1];
  for (int i = 0; i < CH; i++) {
    int idx = base + i;
    if (idx < N_NODES) {
      off[idx] = run;
      cursor[idx] = run;
      run += hist[idx];
    }
  }
  if (tid == 1023) off[N_NODES] = run;  // == E
}

// ---------------- per-layer kernels ----------------

// Fused: scatter (128 edges/block) + prep layer-d (8 nodes/block).
// prep: A fp32; B int8 (exact bound: max_k |x*wb_k| = |x|*wbmax); x-tail fp16.
__global__ void __launch_bounds__(256) scatter_prep_d_kernel(
    const int* __restrict__ edges, int* __restrict__ cursor, int2* __restrict__ se,
    const float* __restrict__ xin,
    const float* __restrict__ Wm1, const float* __restrict__ bm1,
    float* __restrict__ A2, unsigned char* __restrict__ Bq, float* __restrict__ xr) {
  int tid = threadIdx.x;
  // scatter part: 3125 * 128 = 400000 exactly
  if (tid < 128) {
    int e = blockIdx.x * 128 + tid;
    int s = edges[e];
    int d = edges[E_EDGES + e];
    int pos = atomicAdd(&cursor[d], 1);
    se[pos] = make_int2(s, d);
  }
  // prep part
  __shared__ unsigned wbmaxu;
  if (tid == 0) wbmaxu = 0;
  __syncthreads();
  int k = tid;
  float wa = 0.f, wb = 0.f, bm = 0.f;
  if (k < KM) {
    bm = bm1[k];
    wa = Wm1[k];
    wb = Wm1[KM + k];
  }
  float mb = (k < KM) ? fabsf(wb) : 0.f;
#pragma unroll
  for (int s = 1; s < 64; s <<= 1) mb = fmaxf(mb, __shfl_xor(mb, s));
  if ((k & 63) == 0) atomicMax(&wbmaxu, __float_as_uint(mb));
  __syncthreads();
  float wbmax = fmaxf(__uint_as_float(wbmaxu), 1e-30f);
  int n0 = blockIdx.x * 8;
  for (int i = 0; i < 8; i++) {
    int n = n0 + i;
    float xv = xin[n];
    float bBound = fmaxf(fabsf(xv) * wbmax, 1e-30f);
    float xBound = fmaxf(fabsf(xv), 1e-30f);
    size_t rowA = (size_t)n * RS;
    unsigned char* rb = Bq + (size_t)n * RSB;
    if (k == 0) {
      xr[n] = xv;
      A2[rowA + KM] = xv;
      ((__half*)(rb + 208))[0] = __float2half(xv * (32768.f / xBound));
      ((float*)(rb + 248))[0] = bBound / 127.f;
      ((float*)(rb + 248))[1] = xBound / 32768.f;
    }
    if (k < KM) {
      A2[rowA + k] = bm + xv * wa;
      rb[k] = (unsigned char)(signed char)lrintf(xv * wb * (127.f / bBound));
    }
  }
}

// Edge kernel (R18 shape): one thread per (dst-sorted) edge, 128-thread blocks.
// A fp32 (dst-shared, streamed), B int8 256 B gathered line-by-line.
// h_k = relu(A[dst][k] + B8[src][k]*invB); gate = h@Wm2 + bm2 via v_pk_fma_f32;
// gd [c][e] bf16 nt-stores.
template <int CIN>
__global__ void __launch_bounds__(128) edge_kernel(
    const int2* __restrict__ se,
    const float* __restrict__ A2, const unsigned char* __restrict__ Bq,
    const float* __restrict__ Wm2, const float* __restrict__ bm2,
    unsigned short* __restrict__ gd) {
  int e = blockIdx.x * 128 + threadIdx.x;  // grid exact: no bounds check
  int2 sd = se[e];
  int src = sd.x;
  int dst = sd.y;
  const float* Ar = A2 + (size_t)dst * RS;
  const unsigned char* Br = Bq + (size_t)src * RSB;
  float invB = ((const float*)(Br + 248))[0];
  constexpr int NP = (CIN + 1) / 2;
  v2f gate2[NP];
  if constexpr (CIN == 20) {
#pragma unroll
    for (int i = 0; i < NP; i++) gate2[i] = *(const v2f*)(bm2 + 2 * i);
  } else {
    gate2[0].x = bm2[0];
    gate2[0].y = 0.f;
  }
#pragma unroll 2
  for (int k = 0; k < 192; k += 16) {
    float4 a0 = *(const float4*)(Ar + k);
    float4 a1 = *(const float4*)(Ar + k + 4);
    float4 a2 = *(const float4*)(Ar + k + 8);
    float4 a3 = *(const float4*)(Ar + k + 12);
    uint4 braw = *(const uint4*)(Br + k);  // 16 int8
    float4 f0 = i8x4f(braw.x);
    float4 f1 = i8x4f(braw.y);
    float4 f2 = i8x4f(braw.z);
    float4 f3 = i8x4f(braw.w);
    float h[16];
    h[0] = fmaxf(a0.x + f0.x * invB, 0.f);
    h[1] = fmaxf(a0.y + f0.y * invB, 0.f);
    h[2] = fmaxf(a0.z + f0.z * invB, 0.f);
    h[3] = fmaxf(a0.w + f0.w * invB, 0.f);
    h[4] = fmaxf(a1.x + f1.x * invB, 0.f);
    h[5] = fmaxf(a1.y + f1.y * invB, 0.f);
    h[6] = fmaxf(a1.z + f1.z * invB, 0.f);
    h[7] = fmaxf(a1.w + f1.w * invB, 0.f);
    h[8] = fmaxf(a2.x + f2.x * invB, 0.f);
    h[9] = fmaxf(a2.y + f2.y * invB, 0.f);
    h[10] = fmaxf(a2.z + f2.z * invB, 0.f);
    h[11] = fmaxf(a2.w + f2.w * invB, 0.f);
    h[12] = fmaxf(a3.x + f3.x * invB, 0.f);
    h[13] = fmaxf(a3.y + f3.y * invB, 0.f);
    h[14] = fmaxf(a3.z + f3.z * invB, 0.f);
    h[15] = fmaxf(a3.w + f3.w * invB, 0.f);
    if constexpr (CIN == 20) {
#pragma unroll
      for (int j = 0; j < 16; j++) {
        v2f hj;
        hj.x = h[j];
        hj.y = h[j];
        const v2f* w2 = (const v2f*)(Wm2 + (k + j) * 20);
#pragma unroll
        for (int i = 0; i < 10; i++) gate2[i] += hj * w2[i];
      }
    } else {
      float g = gate2[0].x;
#pragma unroll
      for (int j = 0; j < 16; j++) g += h[j] * Wm2[k + j];
      gate2[0].x = g;
    }
  }
  {  // tail k = 192..199
    float4 a0 = *(const float4*)(Ar + 192);
    float4 a1 = *(const float4*)(Ar + 196);
    uint2 braw = *(const uint2*)(Br + 192);
    float4 f01 = i8x4f(braw.x);
    float4 f23 = i8x4f(braw.y);
    float h[8];
    h[0] = fmaxf(a0.x + f01.x * invB, 0.f);
    h[1] = fmaxf(a0.y + f01.y * invB, 0.f);
    h[2] = fmaxf(a0.z + f01.z * invB, 0.f);
    h[3] = fmaxf(a0.w + f01.w * invB, 0.f);
    h[4] = fmaxf(a1.x + f23.x * invB, 0.f);
    h[5] = fmaxf(a1.y + f23.y * invB, 0.f);
    h[6] = fmaxf(a1.z + f23.z * invB, 0.f);
    h[7] = fmaxf(a1.w + f23.w * invB, 0.f);
    if constexpr (CIN == 20) {
#pragma unroll
      for (int j = 0; j < 8; j++) {
        v2f hj;
        hj.x = h[j];
        hj.y = h[j];
        const v2f* w2 = (const v2f*)(Wm2 + (192 + j) * 20);
#pragma unroll
        for (int i = 0; i < 10; i++) gate2[i] += hj * w2[i];
      }
    } else {
      float g = gate2[0].x;
#pragma unroll
      for (int j = 0; j < 8; j++) g += h[j] * Wm2[192 + j];
      gate2[0].x = g;
    }
  }
  // x-diff tails: A fp32, B fp16-scaled; coalesced nontemporal bf16 stores
  float invXb = ((const float*)(Br + 248))[1];
  const __half* xtb = (const __half*)(Br + 208);
  if constexpr (CIN == 20) {
    unsigned wxb[10];
    {
      uint4 s0 = *(const uint4*)(xtb);
      uint4 s1 = *(const uint4*)(xtb + 8);
      uint2 s2 = *(const uint2*)(xtb + 16);
      wxb[0] = s0.x; wxb[1] = s0.y; wxb[2] = s0.z; wxb[3] = s0.w;
      wxb[4] = s1.x; wxb[5] = s1.y; wxb[6] = s1.z; wxb[7] = s1.w;
      wxb[8] = s2.x; wxb[9] = s2.y;
    }
#pragma unroll
    for (int i = 0; i < 10; i++) {
      float2 xa = *(const float2*)(Ar + KM + 2 * i);
      float2 fb = h2f(wxb[i]);
      int c0 = 2 * i, c1 = 2 * i + 1;
      __builtin_nontemporal_store(f2bfr(gate2[i].x * (xa.x - fb.x * invXb)),
                                  gd + (size_t)c0 * E_EDGES + e);
      __builtin_nontemporal_store(f2bfr(gate2[i].y * (xa.y - fb.y * invXb)),
                                  gd + (size_t)c1 * E_EDGES + e);
    }
  } else {
    float xa = Ar[KM];
    float xb = __half2float(xtb[0]) * invXb;
    __builtin_nontemporal_store(f2bfr(gate2[0].x * (xa - xb)), gd + e);
  }
}

// Final-layer edge kernel: computes scalar dot(gate*xd, W2col) per edge and
// wave-segment-reduces over equal-dst runs (1 channel -> cheap), then one
// atomicAdd per run into out[dst]. Kills the final gd round-trip entirely.
__global__ void __launch_bounds__(128) edge_final_kernel(
    const int2* __restrict__ se,
    const float* __restrict__ A2, const unsigned char* __restrict__ Bq,
    const float* __restrict__ Wm2, const float* __restrict__ bm2,
    const float* __restrict__ W2, float* __restrict__ out) {
  int e = blockIdx.x * 128 + threadIdx.x;
  int2 sd = se[e];
  int src = sd.x;
  int dst = sd.y;
  const float* Ar = A2 + (size_t)dst * RS;
  const unsigned char* Br = Bq + (size_t)src * RSB;
  float invB = ((const float*)(Br + 248))[0];
  v2f gate2[10];
#pragma unroll
  for (int i = 0; i < 10; i++) gate2[i] = *(const v2f*)(bm2 + 2 * i);
#pragma unroll 2
  for (int k = 0; k < 192; k += 16) {
    float4 a0 = *(const float4*)(Ar + k);
    float4 a1 = *(const float4*)(Ar + k + 4);
    float4 a2 = *(const float4*)(Ar + k + 8);
    float4 a3 = *(const float4*)(Ar + k + 12);
    uint4 braw = *(const uint4*)(Br + k);
    float4 f0 = i8x4f(braw.x);
    float4 f1 = i8x4f(braw.y);
    float4 f2 = i8x4f(braw.z);
    float4 f3 = i8x4f(braw.w);
    float h[16];
    h[0] = fmaxf(a0.x + f0.x * invB, 0.f);
    h[1] = fmaxf(a0.y + f0.y * invB, 0.f);
    h[2] = fmaxf(a0.z + f0.z * invB, 0.f);
    h[3] = fmaxf(a0.w + f0.w * invB, 0.f);
    h[4] = fmaxf(a1.x + f1.x * invB, 0.f);
    h[5] = fmaxf(a1.y + f1.y * invB, 0.f);
    h[6] = fmaxf(a1.z + f1.z * invB, 0.f);
    h[7] = fmaxf(a1.w + f1.w * invB, 0.f);
    h[8] = fmaxf(a2.x + f2.x * invB, 0.f);
    h[9] = fmaxf(a2.y + f2.y * invB, 0.f);
    h[10] = fmaxf(a2.z + f2.z * invB, 0.f);
    h[11] = fmaxf(a2.w + f2.w * invB, 0.f);
    h[12] = fmaxf(a3.x + f3.x * invB, 0.f);
    h[13] = fmaxf(a3.y + f3.y * invB, 0.f);
    h[14] = fmaxf(a3.z + f3.z * invB, 0.f);
    h[15] = fmaxf(a3.w + f3.w * invB, 0.f);
#pragma unroll
    for (int j = 0; j < 16; j++) {
      v2f hj;
      hj.x = h[j];
      hj.y = h[j];
      const v2f* w2 = (const v2f*)(Wm2 + (k + j) * 20);
#pragma unroll
      for (int i = 0; i < 10; i++) gate2[i] += hj * w2[i];
    }
  }
  {  // tail k = 192..199
    float4 a0 = *(const float4*)(Ar + 192);
    float4 a1 = *(const float4*)(Ar + 196);
    uint2 braw = *(const uint2*)(Br + 192);
    float4 f01 = i8x4f(braw.x);
    float4 f23 = i8x4f(braw.y);
    float h[8];
    h[0] = fmaxf(a0.x + f01.x * invB, 0.f);
    h[1] = fmaxf(a0.y + f01.y * invB, 0.f);
    h[2] = fmaxf(a0.z + f01.z * invB, 0.f);
    h[3] = fmaxf(a0.w + f01.w * invB, 0.f);
    h[4] = fmaxf(a1.x + f23.x * invB, 0.f);
    h[5] = fmaxf(a1.y + f23.y * invB, 0.f);
    h[6] = fmaxf(a1.z + f23.z * invB, 0.f);
    h[7] = fmaxf(a1.w + f23.w * invB, 0.f);
#pragma unroll
    for (int j = 0; j < 8; j++) {
      v2f hj;
      hj.x = h[j];
      hj.y = h[j];
      const v2f* w2 = (const v2f*)(Wm2 + (192 + j) * 20);
#pragma unroll
      for (int i = 0; i < 10; i++) gate2[i] += hj * w2[i];
    }
  }
  // scalar edge contribution: dot(gate * xd, W2)
  float invXb = ((const float*)(Br + 248))[1];
  const __half* xtb = (const __half*)(Br + 208);
  unsigned wxb[10];
  {
    uint4 s0 = *(const uint4*)(xtb);
    uint4 s1 = *(const uint4*)(xtb + 8);
    uint2 s2 = *(const uint2*)(xtb + 16);
    wxb[0] = s0.x; wxb[1] = s0.y; wxb[2] = s0.z; wxb[3] = s0.w;
    wxb[4] = s1.x; wxb[5] = s1.y; wxb[6] = s1.z; wxb[7] = s1.w;
    wxb[8] = s2.x; wxb[9] = s2.y;
  }
  float sv = 0.f;
#pragma unroll
  for (int i = 0; i < 10; i++) {
    float2 xa = *(const float2*)(Ar + KM + 2 * i);
    float2 fb = h2f(wxb[i]);
    sv += gate2[i].x * (xa.x - fb.x * invXb) * W2[2 * i] +
          gate2[i].y * (xa.y - fb.y * invXb) * W2[2 * i + 1];
  }
  // wave-level segmented sum over equal-dst runs (dst-sorted), then 1 atomic/run
  int lane = threadIdx.x & 63;
  bool seg[6];
#pragma unroll
  for (int i = 0; i < 6; i++) {
    int s = 1 << i;
    int od = __shfl_up(dst, s);
    seg[i] = (lane >= s) && (od == dst);
  }
#pragma unroll
  for (int i = 0; i < 6; i++) {
    float o = __shfl_up(sv, 1 << i);
    if (seg[i]) sv += o;
  }
  int dn = __shfl_down(dst, 1);
  bool is_last = (lane == 63) || (dn != dst);
  if (is_last) atomicAdd(out + dst, sv);
}

// finout: adds the node terms to the atomically-accumulated edge sums.
__global__ void finout_kernel(const int* __restrict__ off,
                              const float* __restrict__ xrp,
                              const float* __restrict__ W1, const float* __restrict__ b1,
                              const float* __restrict__ b2,
                              float* __restrict__ out) {
  int n = blockIdx.x * blockDim.x + threadIdx.x;
  if (n >= N_NODES) return;
  float deg = (float)(off[n + 1] - off[n]);
  float v = b1[0] + deg * b2[0];
  const float* xp = xrp + (size_t)n * 20;
#pragma unroll
  for (int c = 0; c < 20; c++) v += xp[c] * W1[c];
  out[n] += v;
}

// afp1: after layer-d edge (gd 1-channel bf16). Per block: 8 nodes.
__global__ void __launch_bounds__(256) afp1_kernel(
    const unsigned short* __restrict__ gd, const int* __restrict__ off,
    const float* __restrict__ xrp,
    const float* __restrict__ W1, const float* __restrict__ b1,
    const float* __restrict__ W2, const float* __restrict__ b2,
    const float* __restrict__ Wm1n, const float* __restrict__ bm1n,
    float* __restrict__ A2, unsigned char* __restrict__ Bq, float* __restrict__ xrn) {
  __shared__ float ag[8], xp[8], degs[8];
  __shared__ float xv[8][21];
  __shared__ unsigned bmaxu[8];
  __shared__ float xmaxs[8];
  int tid = threadIdx.x;
  int n0 = blockIdx.x * 8;
  if (tid < 8) {
    bmaxu[tid] = 0;
    int n = n0 + tid;
    int s = off[n], t = off[n + 1];
    ag[tid] = seg_sum_bf16(gd, s, t);
    xp[tid] = xrp[n];
    degs[tid] = (float)(t - s);
  }
  __syncthreads();
  if (tid < 160) {
    int o = tid >> 3, nl = tid & 7;
    float v = b1[o] + degs[nl] * b2[o] + ag[nl] * W2[o] + xp[nl] * W1[o];
    float r = fmaxf(v, 0.f);
    xv[nl][o] = r;
    xrn[(n0 + nl) * 20 + o] = r;
  }
  __syncthreads();
  if (tid < 8) {
    float m = 0.f;
#pragma unroll
    for (int c = 0; c < 20; c++) m = fmaxf(m, xv[tid][c]);
    xmaxs[tid] = fmaxf(m, 1e-30f);
  }
  int k = tid;
  float aa[8], bb[8];
  if (k < KM) {
    v2f wab[20];
    float bm = bm1n[k];
#pragma unroll
    for (int c = 0; c < 20; c++) {
      wab[c].x = Wm1n[c * KM + k];
      wab[c].y = Wm1n[(20 + c) * KM + k];
    }
#pragma unroll
    for (int nl = 0; nl < 8; nl++) {
      v2f acc;
      acc.x = bm;
      acc.y = 0.f;
#pragma unroll
      for (int c = 0; c < 20; c++) {
        v2f xc;
        xc.x = xv[nl][c];
        xc.y = xv[nl][c];
        acc += xc * wab[c];
      }
      aa[nl] = acc.x;
      bb[nl] = acc.y;
    }
  }
  float mxb[8];
#pragma unroll
  for (int nl = 0; nl < 8; nl++) mxb[nl] = (k < KM) ? fabsf(bb[nl]) : 0.f;
#pragma unroll
  for (int s = 1; s < 64; s <<= 1) {
#pragma unroll
    for (int nl = 0; nl < 8; nl++) mxb[nl] = fmaxf(mxb[nl], __shfl_xor(mxb[nl], s));
  }
  if ((tid & 63) == 0) {
#pragma unroll
    for (int nl = 0; nl < 8; nl++) atomicMax(&bmaxu[nl], __float_as_uint(mxb[nl]));
  }
  __syncthreads();
  if (k < KM) {
#pragma unroll
    for (int nl = 0; nl < 8; nl++) {
      float bmax = fmaxf(__uint_as_float(bmaxu[nl]), 1e-30f);
      float xmax = xmaxs[nl];
      size_t rowA = (size_t)(n0 + nl) * RS;
      unsigned char* rb = Bq + (size_t)(n0 + nl) * RSB;
      A2[rowA + k] = aa[nl];
      rb[k] = (unsigned char)(signed char)lrintf(bb[nl] * (127.f / bmax));
      if (k < 20) {
        A2[rowA + KM + k] = xv[nl][k];
        ((__half*)(rb + 208))[k] = __float2half(xv[nl][k] * (32768.f / xmax));
      }
      if (k == 0) {
        ((float*)(rb + 248))[0] = bmax / 127.f;
        ((float*)(rb + 248))[1] = xmax / 32768.f;
      }
    }
  }
}

// afp20: after a hidden edge (gd 20-channel bf16). Same 3 phases, CIN=20.
__global__ void __launch_bounds__(256) afp20_kernel(
    const unsigned short* __restrict__ gd, const int* __restrict__ off,
    const float* __restrict__ xrp,
    const float* __restrict__ W1, const float* __restrict__ b1,
    const float* __restrict__ W2, const float* __restrict__ b2,
    const float* __restrict__ Wm1n, const float* __restrict__ bm1n,
    float* __restrict__ A2, unsigned char* __restrict__ Bq, float* __restrict__ xrn) {
  __shared__ float ag[8][21], xp[8][21], xv[8][21], degs[8];
  __shared__ unsigned bmaxu[8];
  __shared__ float xmaxs[8];
  int tid = threadIdx.x;
  int n0 = blockIdx.x * 8;
  if (tid < 8) bmaxu[tid] = 0;
  if (tid < 160) {
    int c = tid >> 3, nl = tid & 7;  // adjacent lanes: same c, adjacent n
    int n = n0 + nl;
    int s = off[n], t = off[n + 1];
    ag[nl][c] = seg_sum_bf16(gd + (size_t)c * E_EDGES, s, t);
    xp[nl][c] = xrp[n * 20 + c];
    if (c == 0) degs[nl] = (float)(t - s);
  }
  __syncthreads();
  if (tid < 160) {
    int o = tid >> 3, nl = tid & 7;
    float v = b1[o] + degs[nl] * b2[o];
#pragma unroll
    for (int c = 0; c < 20; c++) {
      v += ag[nl][c] * W2[c * 20 + o] + xp[nl][c] * W1[c * 20 + o];
    }
    float r = fmaxf(v, 0.f);
    xv[nl][o] = r;
    xrn[(n0 + nl) * 20 + o] = r;
  }
  __syncthreads();
  if (tid < 8) {
    float m = 0.f;
#pragma unroll
    for (int c = 0; c < 20; c++) m = fmaxf(m, xv[tid][c]);
    xmaxs[tid] = fmaxf(m, 1e-30f);
  }
  int k = tid;
  float aa[8], bb[8];
  if (k < KM) {
    v2f wab[20];
    float bm = bm1n[k];
#pragma unroll
    for (int c = 0; c < 20; c++) {
      wab[c].x = Wm1n[c * KM + k];
      wab[c].y = Wm1n[(20 + c) * KM + k];
    }
#pragma unroll
    for (int nl = 0; nl < 8; nl++) {
      v2f acc;
      acc.x = bm;
      acc.y = 0.f;
#pragma unroll
      for (int c = 0; c < 20; c++) {
        v2f xc;
        xc.x = xv[nl][c];
        xc.y = xv[nl][c];
        acc += xc * wab[c];
      }
      aa[nl] = acc.x;
      bb[nl] = acc.y;
    }
  }
  float mxb[8];
#pragma unroll
  for (int nl = 0; nl < 8; nl++) mxb[nl] = (k < KM) ? fabsf(bb[nl]) : 0.f;
#pragma unroll
  for (int s = 1; s < 64; s <<= 1) {
#pragma unroll
    for (int nl = 0; nl < 8; nl++) mxb[nl] = fmaxf(mxb[nl], __shfl_xor(mxb[nl], s));
  }
  if ((tid & 63) == 0) {
#pragma unroll
    for (int nl = 0; nl < 8; nl++) atomicMax(&bmaxu[nl], __float_as_uint(mxb[nl]));
  }
  __syncthreads();
  if (k < KM) {
#pragma unroll
    for (int nl = 0; nl < 8; nl++) {
      float bmax = fmaxf(__uint_as_float(bmaxu[nl]), 1e-30f);
      float xmax = xmaxs[nl];
      size_t rowA = (size_t)(n0 + nl) * RS;
      unsigned char* rb = Bq + (size_t)(n0 + nl) * RSB;
      A2[rowA + k] = aa[nl];
      rb[k] = (unsigned char)(signed char)lrintf(bb[nl] * (127.f / bmax));
      if (k < 20) {
        A2[rowA + KM + k] = xv[nl][k];
        ((__half*)(rb + 208))[k] = __float2half(xv[nl][k] * (32768.f / xmax));
      }
      if (k == 0) {
        ((float*)(rb + 248))[0] = bmax / 127.f;
        ((float*)(rb + 248))[1] = xmax / 32768.f;
      }
    }
  }
}

// ---------------- launch ----------------

extern "C" void kernel_launch(void* const* d_in, const int* in_sizes, int n_in,
                              void* d_out, int out_size, void* d_ws, size_t ws_size,
                              hipStream_t stream) {
  const float* features = (const float*)d_in[0];
  const int* edges = (const int*)d_in[1];
  // d_in[2] = weights (unused by reference)

  const float *dW1 = (const float*)d_in[3], *db1 = (const float*)d_in[4],
              *dWm1 = (const float*)d_in[5], *dbm1 = (const float*)d_in[6],
              *dWm2 = (const float*)d_in[7], *dbm2 = (const float*)d_in[8],
              *dW2 = (const float*)d_in[9], *db2 = (const float*)d_in[10];
  const float *hW1 = (const float*)d_in[11], *hb1 = (const float*)d_in[12],
              *hWm1 = (const float*)d_in[13], *hbm1 = (const float*)d_in[14],
              *hWm2 = (const float*)d_in[15], *hbm2 = (const float*)d_in[16],
              *hW2 = (const float*)d_in[17], *hb2 = (const float*)d_in[18];
  const float *oW1 = (const float*)d_in[19], *ob1 = (const float*)d_in[20],
              *oWm1 = (const float*)d_in[21], *obm1 = (const float*)d_in[22],
              *oWm2 = (const float*)d_in[23], *obm2 = (const float*)d_in[24],
              *oW2 = (const float*)d_in[25], *ob2 = (const float*)d_in[26];

  // workspace layout (float units)
  float* fws = (float*)d_ws;
  size_t o = 0;
  float* A2 = fws + o;                           o += (size_t)N_NODES * RS;       // 5.6M
  unsigned char* Bq = (unsigned char*)(fws + o); o += (size_t)N_NODES * RSB / 4;  // 1.6M floats
  unsigned short* gd = (unsigned short*)(fws + o); o += (size_t)20 * E_EDGES / 2; // 4.0M floats (bf16)
  float* xrA = fws + o;                          o += (size_t)N_NODES * 20;
  float* xrB = fws + o;                          o += (size_t)N_NODES * 20;
  int* ip = (int*)(fws + o);
  int* hist = ip;   ip += N_NODES;
  int* off = ip;    ip += N_NODES + 4;
  int* cursor = ip; ip += N_NODES;
  int2* se = (int2*)ip;

  const int B256 = 256;
  const int EDGE_G = E_EDGES / 128;  // 3125, exact (128-thread blocks)
  const int NODE8_G = N_NODES / 8;   // 3125, exact
  const int NODE_G = (N_NODES + B256 - 1) / B256;

  // zero d_out (edge_final accumulates into it atomically)
  (void)hipMemsetAsync(d_out, 0, (size_t)N_NODES * sizeof(float), stream);
  // build dst-sorted edge list + CSR offsets (recomputed every launch)
  (void)hipMemsetAsync(hist, 0, N_NODES * sizeof(int), stream);
  hist_kernel<<<(E_EDGES + B256 - 1) / B256, B256, 0, stream>>>(edges, hist);
  scan_kernel<<<1, 1024, 0, stream>>>(hist, off, cursor);

  // layer d: 1 -> 20 (scatter fused into prep)
  scatter_prep_d_kernel<<<NODE8_G, B256, 0, stream>>>(edges, cursor, se, features,
                                                      dWm1, dbm1, A2, Bq, xrA);
  edge_kernel<1><<<EDGE_G, 128, 0, stream>>>(se, A2, Bq, dWm2, dbm2, gd);
  afp1_kernel<<<NODE8_G, B256, 0, stream>>>(gd, off, xrA, dW1, db1, dW2, db2,
                                            hWm1, hbm1, A2, Bq, xrB);

  // hidden1
  edge_kernel<20><<<EDGE_G, 128, 0, stream>>>(se, A2, Bq, hWm2, hbm2, gd);
  afp20_kernel<<<NODE8_G, B256, 0, stream>>>(gd, off, xrB, hW1, hb1, hW2, hb2,
                                             hWm1, hbm1, A2, Bq, xrA);
  // hidden2
  edge_kernel<20><<<EDGE_G, 128, 0, stream>>>(se, A2, Bq, hWm2, hbm2, gd);
  afp20_kernel<<<NODE8_G, B256, 0, stream>>>(gd, off, xrA, hW1, hb1, hW2, hb2,
                                             hWm1, hbm1, A2, Bq, xrB);
  // hidden3 -> preps output layer (oWm1)
  edge_kernel<20><<<EDGE_G, 128, 0, stream>>>(se, A2, Bq, hWm2, hbm2, gd);
  afp20_kernel<<<NODE8_G, B256, 0, stream>>>(gd, off, xrB, hW1, hb1, hW2, hb2,
                                             oWm1, obm1, A2, Bq, xrA);
  // output layer: 20 -> 1, gd-free (scalar atomics into d_out) + node terms
  edge_final_kernel<<<EDGE_G, 128, 0, stream>>>(se, A2, Bq, oWm2, obm2, oW2,
                                                (float*)d_out);
  finout_kernel<<<NODE_G, B256, 0, stream>>>(off, xrA, oW1, ob1, ob2,
                                             (float*)d_out);
}